// Round 12
// baseline (218.430 us; speedup 1.0000x reference)
//
#include <hip/hip_runtime.h>
#include <hip/hip_bf16.h>

#define BB 8
#define SS 4096
#define CC 512
#define NTOK (BB*SS)   // 32768
#define QKVS 1664      // q(512) | k(512) | v(512) | qg(128)

typedef __attribute__((ext_vector_type(8))) short bf16x8;
typedef __attribute__((ext_vector_type(4))) float f32x4;
typedef __attribute__((ext_vector_type(4))) short s16x4;

__device__ __forceinline__ float bf2f(short s) {
  return __uint_as_float(((unsigned)(unsigned short)s) << 16);
}
__device__ __forceinline__ short f2bf(float f) {
  __hip_bfloat16 h = __float2bfloat16(f);
  return *reinterpret_cast<short*>(&h);
}

__device__ __forceinline__ f32x4 pv_mfma(s16x4 a, s16x4 b, f32x4 c) {
#if __has_builtin(__builtin_amdgcn_mfma_f32_16x16x16bf16_1k)
  return __builtin_amdgcn_mfma_f32_16x16x16bf16_1k(a, b, c, 0, 0, 0);
#else
  f32x4 d;
  asm volatile("v_mfma_f32_16x16x16_bf16 %0, %1, %2, %3\n\ts_nop 7\n\ts_nop 7"
               : "=v"(d) : "v"(a), "v"(b), "v"(c));
  return d;
#endif
}

// async global -> LDS, 16B per lane; LDS dest is wave-uniform base + lane*16
__device__ __forceinline__ void gload_lds16(const short* g, short* l) {
  __builtin_amdgcn_global_load_lds(
      (const __attribute__((address_space(1))) unsigned int*)g,
      (__attribute__((address_space(3))) unsigned int*)l, 16, 0, 0);
}

// ---------------- smalls: WqWg fold (c-split x4), kg+kgo, bqg ----------------
// blocks 0..1023: fold -> WtQKV rows [1536,1664): WtQG[n][k] = sum_c Wq[k][c]*Wg[c][n]
// blocks 1024..1055: kg[b][g][:], kgo[b][g][:]
// block 1056: bqg[n] = bg[n] + sum_c bq[c]*Wg[c][n] -> bqkv[1536+n]
__global__ __launch_bounds__(256) void smalls_kernel(
    const float* __restrict__ Wq, const float* __restrict__ Wg,
    const float* __restrict__ bq, const float* __restrict__ bg,
    const float* __restrict__ Wgo, const float* __restrict__ x,
    short* __restrict__ WtQKV, float* __restrict__ bqkv,
    float* __restrict__ kg, float* __restrict__ kgo)
{
  __shared__ float kr[128];
  const int t = threadIdx.x;
  if (blockIdx.x < 1024) {                    // fold: 4 threads per output
    const int o = (blockIdx.x * 256 + t) >> 2;
    const int q = t & 3;
    const int n = o >> 9, k = o & 511;
    const float* wqr = &Wq[(size_t)k * 512];
    float s = 0.f;
    const int c0 = q * 128;
    for (int c = 0; c < 128; c++) s += wqr[c0 + c] * Wg[(size_t)(c0 + c) * 128 + n];
    s += __shfl_xor(s, 1);
    s += __shfl_xor(s, 2);
    if (q == 0) WtQKV[(size_t)(1536 + n) * 512 + k] = f2bf(s);
  } else if (blockIdx.x < 1056) {             // kg + kgo
    const int bg_ = blockIdx.x - 1024;        // (b = bg_>>2, g = bg_&3)
    const int b = bg_ >> 2, g = bg_ & 3;
    const int gidx[4] = {0, 1365, 2730, 4095};
    const float* xr = &x[((size_t)b * SS + gidx[g]) * CC];
    if (t < 128) {
      float sv = bg[t];
      for (int c = 0; c < CC; c++) sv += xr[c] * Wg[c * 128 + t];
      kr[t] = sv;
      kg[bg_ * 128 + t] = sv;
    }
    __syncthreads();
    for (int c = t; c < 512; c += 256) {
      float sv = 0.f;
      for (int d = 0; d < 128; d++) sv += kr[d] * Wgo[d * 512 + c];
      kgo[bg_ * 512 + c] = sv;
    }
  } else {                                    // bqg: 2 threads per output
    const int o = t >> 1, h = t & 1;
    float s = h ? 0.f : bg[o];
    const int c0 = h * 256;
    for (int c = 0; c < 256; c++) s += bq[c0 + c] * Wg[(size_t)(c0 + c) * 128 + o];
    s += __shfl_xor(s, 1);
    if (h == 0) bqkv[1536 + o] = s;
  }
}

// ---------------- prep: transpose+cast weights, qkv bias concat (pure) ----------------
__global__ __launch_bounds__(256) void prep_weights(
    const float* __restrict__ Wq, const float* __restrict__ Wk, const float* __restrict__ Wv,
    const float* __restrict__ Wo,
    const float* __restrict__ bq, const float* __restrict__ bk, const float* __restrict__ bv,
    short* __restrict__ WtQKV, short* __restrict__ WtO, float* __restrict__ bqkv)
{
  int i = blockIdx.x * 256 + threadIdx.x;
  if (i < 1536 * 512) {                  // WtQKV[n][k] = W*(k, n%512)
    int n = i >> 9, k = i & 511;
    const float* W = (n < 512) ? Wq : (n < 1024) ? Wk : Wv;
    WtQKV[i] = f2bf(W[k * 512 + (n & 511)]);
  }
  if (i < 512 * 512) {                   // WtO[n][k] = Wo[k][n]
    int n = i >> 9, k = i & 511;
    WtO[i] = f2bf(Wo[k * 512 + n]);
  }
  if (i < 1536) {
    bqkv[i] = (i < 512) ? bq[i] : (i < 1024) ? bk[i - 512] : bv[i - 1024];
  }
}

// ---------------- fused: cast x fp32->bf16 + channel pool (avg,max) — pure ----------
__global__ __launch_bounds__(256) void cast_pool_kernel(const float* __restrict__ x,
                                                        short* __restrict__ xb,
                                                        float* __restrict__ pavg,
                                                        float* __restrict__ pmax)
{
  int tok = blockIdx.x * 4 + (threadIdx.x >> 6);
  int lane = threadIdx.x & 63;
  const float* xr = &x[(size_t)tok * CC];
  float4 a = *(const float4*)&xr[lane * 4];
  float4 b = *(const float4*)&xr[256 + lane * 4];
  s16x4 oa, ob;
  oa[0] = f2bf(a.x); oa[1] = f2bf(a.y); oa[2] = f2bf(a.z); oa[3] = f2bf(a.w);
  ob[0] = f2bf(b.x); ob[1] = f2bf(b.y); ob[2] = f2bf(b.z); ob[3] = f2bf(b.w);
  *(s16x4*)&xb[(size_t)tok * CC + lane * 4] = oa;
  *(s16x4*)&xb[(size_t)tok * CC + 256 + lane * 4] = ob;
  float s = (a.x + a.y) + (a.z + a.w) + (b.x + b.y) + (b.z + b.w);
  float m = fmaxf(fmaxf(fmaxf(a.x, a.y), fmaxf(a.z, a.w)),
                  fmaxf(fmaxf(b.x, b.y), fmaxf(b.z, b.w)));
#pragma unroll
  for (int off = 32; off; off >>= 1) {
    s += __shfl_down(s, off);
    m = fmaxf(m, __shfl_down(m, off));
  }
  if (lane == 0) { pavg[tok] = s * (1.0f / CC); pmax[tok] = m; }
}

// ---------------- bf16 MFMA GEMM, BK=64 single-buffer, XOR-swizzled LDS (r8 proven) ----
// C[M,N] = A[M,512] @ Wt[N,512]^T + bias. tile 128x128, 4 waves (2x2), wave 64x64.
// LDS rows 128B -> both-sides involution (rule 21): source chunk ^= row&7, reader ^= (row&7)<<4 B.
template<int OUT_BF16, int SWZ>
__global__ __launch_bounds__(256, 3) void gemm_kernel(
    const short* __restrict__ A,
    const short* __restrict__ Wt,
    const float* __restrict__ bias,
    void* __restrict__ Cp, int ldc, int nx)
{
  __shared__ short As[128 * 64];
  __shared__ short Bs[128 * 64];
  int id = blockIdx.x;
  if (SWZ) {                              // T1: contiguous tile chunk per XCD (grid%8==0)
    const int cpx = gridDim.x >> 3;
    id = (id & 7) * cpx + (id >> 3);
  }
  const int n0 = (id % nx) * 128;
  const int m0 = (id / nx) * 128;
  const int t = threadIdx.x;
  const int lane = t & 63, w = t >> 6;
  const int wm = (w >> 1) * 64, wn = (w & 1) * 64;
  const int lr = lane & 15;
  const int g8b = (lane >> 4) * 16;       // byte offset of k-frag (8 bf16)
  const int xorb = (lr & 7) << 4;         // reader swizzle (row&7)<<4 bytes

  const int srow = w * 8 + (lane >> 3);
  const int scol = (((lane & 7) ^ (lane >> 3)) << 4) >> 1;    // elems
  const short* Ag = A + (size_t)(m0 + srow) * 512 + scol;
  const short* Bg = Wt + (size_t)(n0 + srow) * 512 + scol;
  short* Al = &As[(w * 8) * 64];
  short* Bl = &Bs[(w * 8) * 64];

  f32x4 acc[4][4];
#pragma unroll
  for (int i = 0; i < 4; i++)
#pragma unroll
    for (int j = 0; j < 4; j++) acc[i][j] = (f32x4){0.f, 0.f, 0.f, 0.f};

  for (int k0 = 0; k0 < 512; k0 += 64) {
#pragma unroll
    for (int s = 0; s < 4; s++) {
      gload_lds16(Ag + k0 + s * (32 * 512), Al + s * (32 * 64));
      gload_lds16(Bg + k0 + s * (32 * 512), Bl + s * (32 * 64));
    }
    __syncthreads();                     // implicit vmcnt(0) drain
#pragma unroll
    for (int kk = 0; kk < 2; kk++) {
      bf16x8 af[4], bfr[4];
      const int ko = ((kk * 64 + g8b) ^ xorb) >> 1;   // swizzled elem offset in row
#pragma unroll
      for (int mt = 0; mt < 4; mt++) af[mt]  = *(bf16x8*)&As[(wm + mt * 16 + lr) * 64 + ko];
#pragma unroll
      for (int nt = 0; nt < 4; nt++) bfr[nt] = *(bf16x8*)&Bs[(wn + nt * 16 + lr) * 64 + ko];
#pragma unroll
      for (int mt = 0; mt < 4; mt++)
#pragma unroll
        for (int nt = 0; nt < 4; nt++)
          acc[mt][nt] = __builtin_amdgcn_mfma_f32_16x16x32_bf16(af[mt], bfr[nt], acc[mt][nt], 0, 0, 0);
    }
    __syncthreads();
  }

  const int cr = (lane >> 4) * 4;
#pragma unroll
  for (int nt = 0; nt < 4; nt++) {
    int col = n0 + wn + nt * 16 + lr;
    float bv = bias[col];
#pragma unroll
    for (int mt = 0; mt < 4; mt++) {
      int row = m0 + wm + mt * 16 + cr;
#pragma unroll
      for (int j = 0; j < 4; j++) {
        float v = acc[mt][nt][j] + bv;
        if (OUT_BF16) ((short*)Cp)[(size_t)(row + j) * ldc + col] = f2bf(v);
        else          ((float*)Cp)[(size_t)(row + j) * ldc + col] = v;
      }
    }
  }
}

// ---------------- fused windowed attention + combine (v4, unchanged from r11) --------
__global__ __launch_bounds__(256, 4) void winattn_combine_kernel(
    const short* __restrict__ qkvb, const short* __restrict__ xb,
    const float* __restrict__ kg, const float* __restrict__ kgo,
    const float* __restrict__ bgo, const float* __restrict__ pavg,
    const float* __restrict__ pmax, const float* __restrict__ conv_w,
    short* __restrict__ y)
{
  __shared__ short vs[2][16][512];            // V then xl, row-linear, data swizzled
  __shared__ float4 esm[32];
  __shared__ float gateb[32];
  const int t = threadIdx.x;
  const int lane = t & 63, w = t >> 6;
  const int t0b = blockIdx.x * 32;            // block token base
  const int bb = t0b >> 12;                   // batch
  const int win = w >> 1, half = w & 1;
  const int t0 = t0b + win * 16;              // window token base

  // ---- V stage: wave covers rows half*8..+7 of its window; chunk l -> l^(r&7) ----
  {
    const int rb = half * 8;
#pragma unroll
    for (int i = 0; i < 8; i++) {
      const int r = rb + i;
      const short* vrow = &qkvb[(size_t)(t0 + r) * QKVS + 1024];
      gload_lds16(vrow + ((lane ^ (r & 7)) << 3), &vs[win][r][0]);
    }
  }

  // ---- QK^T (swapped, 2 acc chains) ----
  const int qrow = lane & 15;
  const int grp8 = (lane >> 4) * 8;
  const int krow = (lane >> 4) * 4;
  const int colo = lane & 15;

  const short* kqbase = &qkvb[(size_t)(t0 + qrow) * QKVS];
  f32x4 accA = (f32x4){0.f, 0.f, 0.f, 0.f};
  f32x4 accB = (f32x4){0.f, 0.f, 0.f, 0.f};
#pragma unroll
  for (int k0 = 0; k0 < 512; k0 += 64) {
    bf16x8 kf0 = *(const bf16x8*)&kqbase[512 + k0 + grp8];
    bf16x8 qf0 = *(const bf16x8*)&kqbase[k0 + grp8];
    bf16x8 kf1 = *(const bf16x8*)&kqbase[512 + k0 + 32 + grp8];
    bf16x8 qf1 = *(const bf16x8*)&kqbase[k0 + 32 + grp8];
    accA = __builtin_amdgcn_mfma_f32_16x16x32_bf16(kf0, qf0, accA, 0, 0, 0);
    accB = __builtin_amdgcn_mfma_f32_16x16x32_bf16(kf1, qf1, accB, 0, 0, 0);
  }

  // ---- gattn scores + conv gate: wave w -> tokens w*8..w*8+7, 8 lanes per token ----
  {
    const int tl = w * 8 + (lane >> 3);       // block-local token
    const int sub = lane & 7;                 // 16-elem slice
    const short* qr = &qkvb[(size_t)(t0b + tl) * QKVS + 1536 + sub * 16];
    bf16x8 qv0 = *(const bf16x8*)&qr[0];
    bf16x8 qv1 = *(const bf16x8*)&qr[8];
    const float* kr = &kg[bb * 512 + sub * 16];
    float p[4];
#pragma unroll
    for (int g = 0; g < 4; g++) {
      float4 ka = *(const float4*)&kr[g * 128];
      float4 kbv = *(const float4*)&kr[g * 128 + 4];
      float4 kc = *(const float4*)&kr[g * 128 + 8];
      float4 kd = *(const float4*)&kr[g * 128 + 12];
      float s = bf2f(qv0[0]) * ka.x + bf2f(qv0[1]) * ka.y + bf2f(qv0[2]) * ka.z + bf2f(qv0[3]) * ka.w
              + bf2f(qv0[4]) * kbv.x + bf2f(qv0[5]) * kbv.y + bf2f(qv0[6]) * kbv.z + bf2f(qv0[7]) * kbv.w
              + bf2f(qv1[0]) * kc.x + bf2f(qv1[1]) * kc.y + bf2f(qv1[2]) * kc.z + bf2f(qv1[3]) * kc.w
              + bf2f(qv1[4]) * kd.x + bf2f(qv1[5]) * kd.y + bf2f(qv1[6]) * kd.z + bf2f(qv1[7]) * kd.w;
      p[g] = s;
    }
#pragma unroll
    for (int off = 1; off < 8; off <<= 1) {
#pragma unroll
      for (int g = 0; g < 4; g++) p[g] += __shfl_xor(p[g], off);
    }
    if (sub == 0) {
      const float gs = 0.08838834764831845f;  // 1/sqrt(128)
      float p0 = p[0] * gs, p1 = p[1] * gs, p2 = p[2] * gs, p3 = p[3] * gs;
      float mx = fmaxf(fmaxf(p0, p1), fmaxf(p2, p3));
      float e0 = __expf(p0 - mx), e1 = __expf(p1 - mx), e2 = __expf(p2 - mx), e3 = __expf(p3 - mx);
      float inv = 1.0f / (e0 + e1 + e2 + e3);
      esm[tl] = make_float4(e0 * inv, e1 * inv, e2 * inv, e3 * inv);
      int s = (t0b + tl) & 4095;
      float g = 0.f;
#pragma unroll
      for (int tk = 0; tk < 7; tk++) {
        int ss = s + tk - 3;
        if (ss >= 0 && ss < SS)
          g += conv_w[tk] * pavg[bb * SS + ss] + conv_w[7 + tk] * pmax[bb * SS + ss];
      }
      gateb[tl] = 1.0f / (1.0f + __expf(-g));
    }
  }

  // ---- softmax over 16 keys ----
  const float scale = 0.04419417382415922f;   // 1/sqrt(512)
  float s0 = (accA[0] + accB[0]) * scale, s1 = (accA[1] + accB[1]) * scale;
  float s2 = (accA[2] + accB[2]) * scale, s3 = (accA[3] + accB[3]) * scale;
  float m = fmaxf(fmaxf(s0, s1), fmaxf(s2, s3));
  m = fmaxf(m, __shfl_xor(m, 16));
  m = fmaxf(m, __shfl_xor(m, 32));
  float e0 = __expf(s0 - m), e1 = __expf(s1 - m), e2 = __expf(s2 - m), e3 = __expf(s3 - m);
  float sum = e0 + e1 + e2 + e3;
  sum += __shfl_xor(sum, 16);
  sum += __shfl_xor(sum, 32);
  float inv = 1.0f / sum;
  s16x4 pa;
  pa[0] = f2bf(e0 * inv); pa[1] = f2bf(e1 * inv);
  pa[2] = f2bf(e2 * inv); pa[3] = f2bf(e3 * inv);

  __syncthreads();                            // drains V gloads; publishes esm/gateb

  // ---- PV: read V from LDS (swizzled), mfma, overwrite consumed subtile with xl ----
#pragma unroll
  for (int ct = 0; ct < 16; ct++) {
    const int cb = (half * 256 + ct * 16 + colo) * 2;   // byte offset in row
    s16x4 bf;
#pragma unroll
    for (int u = 0; u < 4; u++) {
      const int r = krow + u;
      bf[u] = vs[win][r][(cb ^ ((r & 7) << 4)) >> 1];
    }
    f32x4 d = pv_mfma(pa, bf, (f32x4){0.f, 0.f, 0.f, 0.f});
#pragma unroll
    for (int jj = 0; jj < 4; jj++) {
      const int r = krow + jj;                          // D row = q index
      vs[win][r][(cb ^ ((r & 7) << 4)) >> 1] = f2bf(d[jj]);
    }
  }
  __syncthreads();

  // ---- vectorized combine: thread -> (row r=t>>3, cols (t&7)*8 + 64*it) ----
  const int r = t >> 3;
  const int rowg = t0b + r;
  const int winr = r >> 4, rr = r & 15;
  const float4 e = esm[r];
  const float g = gateb[r];
  const float* kgr = &kgo[bb * 2048];
  const short* xrow = &xb[(size_t)rowg * CC];
  const short* xlrow = &vs[winr][rr][0];
  short* yrow = &y[(size_t)rowg * CC];
#pragma unroll
  for (int it = 0; it < 8; it++) {
    const int c = (t & 7) * 8 + it * 64;
    bf16x8 xv  = *(const bf16x8*)&xrow[c];
    bf16x8 xlv = *(const bf16x8*)&xlrow[((c * 2) ^ ((rr & 7) << 4)) >> 1];
    float4 k0a = *(const float4*)&kgr[c],        k0b = *(const float4*)&kgr[c + 4];
    float4 k1a = *(const float4*)&kgr[512 + c],  k1b = *(const float4*)&kgr[512 + c + 4];
    float4 k2a = *(const float4*)&kgr[1024 + c], k2b = *(const float4*)&kgr[1024 + c + 4];
    float4 k3a = *(const float4*)&kgr[1536 + c], k3b = *(const float4*)&kgr[1536 + c + 4];
    float4 ba  = *(const float4*)&bgo[c],        bbv = *(const float4*)&bgo[c + 4];
    float xg[8];
    xg[0] = e.x * k0a.x + e.y * k1a.x + e.z * k2a.x + e.w * k3a.x + ba.x;
    xg[1] = e.x * k0a.y + e.y * k1a.y + e.z * k2a.y + e.w * k3a.y + ba.y;
    xg[2] = e.x * k0a.z + e.y * k1a.z + e.z * k2a.z + e.w * k3a.z + ba.z;
    xg[3] = e.x * k0a.w + e.y * k1a.w + e.z * k2a.w + e.w * k3a.w + ba.w;
    xg[4] = e.x * k0b.x + e.y * k1b.x + e.z * k2b.x + e.w * k3b.x + bbv.x;
    xg[5] = e.x * k0b.y + e.y * k1b.y + e.z * k2b.y + e.w * k3b.y + bbv.y;
    xg[6] = e.x * k0b.z + e.y * k1b.z + e.z * k2b.z + e.w * k3b.z + bbv.z;
    xg[7] = e.x * k0b.w + e.y * k1b.w + e.z * k2b.w + e.w * k3b.w + bbv.w;
    bf16x8 ov;
#pragma unroll
    for (int u = 0; u < 8; u++)
      ov[u] = f2bf((bf2f(xv[u]) + bf2f(xlv[u]) + xg[u]) * g);
    *(bf16x8*)&yrow[c] = ov;
  }
}

// ---------------- launcher ----------------
extern "C" void kernel_launch(void* const* d_in, const int* in_sizes, int n_in,
                              void* d_out, int out_size, void* d_ws, size_t ws_size,
                              hipStream_t stream)
{
  const float* x     = (const float*)d_in[0];
  const float* Wq    = (const float*)d_in[1];
  const float* bq    = (const float*)d_in[2];
  const float* Wk    = (const float*)d_in[3];
  const float* bk    = (const float*)d_in[4];
  const float* Wv    = (const float*)d_in[5];
  const float* bv    = (const float*)d_in[6];
  const float* Wo    = (const float*)d_in[7];
  const float* bo    = (const float*)d_in[8];
  const float* Wg    = (const float*)d_in[9];
  const float* bg    = (const float*)d_in[10];
  const float* Wgo   = (const float*)d_in[11];
  const float* bgo   = (const float*)d_in[12];
  const float* convw = (const float*)d_in[13];
  float* out = (float*)d_out;

  char* ws = (char*)d_ws;
  size_t off = 0;
  auto alloc = [&](size_t bytes) -> void* {
    void* p = ws + off;
    off += (bytes + 255) & ~(size_t)255;
    return p;
  };
  short* xb    = (short*)alloc((size_t)NTOK * CC * 2);           // 33.5 MB
  short* qkvb  = (short*)alloc((size_t)NTOK * QKVS * 2);         // 109 MB
  short* WtQKV = (short*)alloc((size_t)QKVS * 512 * 2);          // [q|k|v|WqWg] rows
  short* WtO   = (short*)alloc((size_t)512 * 512 * 2);
  float* bqkv  = (float*)alloc(QKVS * 4);
  float* kg    = (float*)alloc(8 * 4 * 128 * 4);
  float* kgo   = (float*)alloc(8 * 4 * 512 * 4);
  float* pavg  = (float*)alloc((size_t)NTOK * 4);
  float* pmax  = (float*)alloc((size_t)NTOK * 4);
  short* ybuf  = (short*)alloc((size_t)NTOK * CC * 2);           // 33.5 MB (final y)

  smalls_kernel<<<1057, 256, 0, stream>>>(Wq, Wg, bq, bg, Wgo, x,
                                          WtQKV, bqkv, kg, kgo);
  prep_weights<<<3072, 256, 0, stream>>>(Wq, Wk, Wv, Wo, bq, bk, bv,
                                         WtQKV, WtO, bqkv);
  cast_pool_kernel<<<NTOK / 4, 256, 0, stream>>>(x, xb, pavg, pmax);

  // qkv|qg = x @ [Wq|Wk|Wv|WqWg] + [bq|bk|bv|bqg]  (M=32768, N=1664), nwg=3328
  gemm_kernel<1, 1><<<13 * 256, 256, 0, stream>>>(xb, WtQKV, bqkv, qkvb, QKVS, 13);

  // fused window-attention + global-attn combine + gate -> y (bf16)
  winattn_combine_kernel<<<NTOK / 32, 256, 0, stream>>>(qkvb, xb, kg, kgo, bgo,
                                                        pavg, pmax, convw, ybuf);

  // out = y @ Wo + bo  (M=32768, N=512, fp32 out), nwg=1024
  gemm_kernel<0, 1><<<4 * 256, 256, 0, stream>>>(ybuf, WtO, bo, out, CC, 4);
}

// Round 13
// 211.583 us; speedup vs baseline: 1.0324x; 1.0324x over previous
//
#include <hip/hip_runtime.h>
#include <hip/hip_bf16.h>

#define BB 8
#define SS 4096
#define CC 512
#define NTOK (BB*SS)   // 32768
#define QKVS 1664      // q(512) | k(512) | v(512) | qg(128)

typedef __attribute__((ext_vector_type(8))) short bf16x8;
typedef __attribute__((ext_vector_type(4))) float f32x4;
typedef __attribute__((ext_vector_type(4))) short s16x4;

__device__ __forceinline__ float bf2f(short s) {
  return __uint_as_float(((unsigned)(unsigned short)s) << 16);
}
__device__ __forceinline__ short f2bf(float f) {
  __hip_bfloat16 h = __float2bfloat16(f);
  return *reinterpret_cast<short*>(&h);
}

__device__ __forceinline__ f32x4 pv_mfma(s16x4 a, s16x4 b, f32x4 c) {
#if __has_builtin(__builtin_amdgcn_mfma_f32_16x16x16bf16_1k)
  return __builtin_amdgcn_mfma_f32_16x16x16bf16_1k(a, b, c, 0, 0, 0);
#else
  f32x4 d;
  asm volatile("v_mfma_f32_16x16x16_bf16 %0, %1, %2, %3\n\ts_nop 7\n\ts_nop 7"
               : "=v"(d) : "v"(a), "v"(b), "v"(c));
  return d;
#endif
}

// async global -> LDS, 16B per lane; LDS dest is wave-uniform base + lane*16
__device__ __forceinline__ void gload_lds16(const short* g, short* l) {
  __builtin_amdgcn_global_load_lds(
      (const __attribute__((address_space(1))) unsigned int*)g,
      (__attribute__((address_space(3))) unsigned int*)l, 16, 0, 0);
}

// ---------------- front: cast_pool + weight prep + fold + kg/kgo + bqg, ONE launch ----
// blocks [0,8192):        cast x->bf16 + channel pool (4 tokens/block)
// blocks [8192,11264):    transpose+cast WtQKV rows 0-1535, WtO, bqkv concat
// blocks [11264,12288):   WqWg fold -> WtQKV rows [1536,1664), 4 threads/output
// blocks [12288,12320):   kg+kgo per (b,g)
// block  12320:           bqg -> bqkv[1536+n]
__global__ __launch_bounds__(256) void front_kernel(
    const float* __restrict__ x,
    const float* __restrict__ Wq, const float* __restrict__ Wk, const float* __restrict__ Wv,
    const float* __restrict__ Wo, const float* __restrict__ Wg,
    const float* __restrict__ bq, const float* __restrict__ bk, const float* __restrict__ bv,
    const float* __restrict__ bg, const float* __restrict__ Wgo,
    short* __restrict__ xb, float* __restrict__ pavg, float* __restrict__ pmax,
    short* __restrict__ WtQKV, short* __restrict__ WtO, float* __restrict__ bqkv,
    float* __restrict__ kg, float* __restrict__ kgo)
{
  __shared__ float kr[128];
  const int t = threadIdx.x;
  const int bid = blockIdx.x;

  if (bid < 8192) {                           // ---- cast + pool ----
    int tok = bid * 4 + (t >> 6);
    int lane = t & 63;
    const float* xr = &x[(size_t)tok * CC];
    float4 a = *(const float4*)&xr[lane * 4];
    float4 b = *(const float4*)&xr[256 + lane * 4];
    s16x4 oa, ob;
    oa[0] = f2bf(a.x); oa[1] = f2bf(a.y); oa[2] = f2bf(a.z); oa[3] = f2bf(a.w);
    ob[0] = f2bf(b.x); ob[1] = f2bf(b.y); ob[2] = f2bf(b.z); ob[3] = f2bf(b.w);
    *(s16x4*)&xb[(size_t)tok * CC + lane * 4] = oa;
    *(s16x4*)&xb[(size_t)tok * CC + 256 + lane * 4] = ob;
    float s = (a.x + a.y) + (a.z + a.w) + (b.x + b.y) + (b.z + b.w);
    float m = fmaxf(fmaxf(fmaxf(a.x, a.y), fmaxf(a.z, a.w)),
                    fmaxf(fmaxf(b.x, b.y), fmaxf(b.z, b.w)));
#pragma unroll
    for (int off = 32; off; off >>= 1) {
      s += __shfl_down(s, off);
      m = fmaxf(m, __shfl_down(m, off));
    }
    if (lane == 0) { pavg[tok] = s * (1.0f / CC); pmax[tok] = m; }
  } else if (bid < 11264) {                   // ---- weight transpose/cast ----
    int i = (bid - 8192) * 256 + t;
    if (i < 1536 * 512) {                     // WtQKV[n][k] = W*(k, n%512)
      int n = i >> 9, k = i & 511;
      const float* W = (n < 512) ? Wq : (n < 1024) ? Wk : Wv;
      WtQKV[i] = f2bf(W[k * 512 + (n & 511)]);
    }
    if (i < 512 * 512) {                      // WtO[n][k] = Wo[k][n]
      int n = i >> 9, k = i & 511;
      WtO[i] = f2bf(Wo[k * 512 + n]);
    }
    if (i < 1536) {
      bqkv[i] = (i < 512) ? bq[i] : (i < 1024) ? bk[i - 512] : bv[i - 1024];
    }
  } else if (bid < 12288) {                   // ---- WqWg fold, 4 threads/output ----
    const int o = ((bid - 11264) * 256 + t) >> 2;
    const int q = t & 3;
    const int n = o >> 9, k = o & 511;
    const float* wqr = &Wq[(size_t)k * 512];
    float s = 0.f;
    const int c0 = q * 128;
    for (int c = 0; c < 128; c++) s += wqr[c0 + c] * Wg[(size_t)(c0 + c) * 128 + n];
    s += __shfl_xor(s, 1);
    s += __shfl_xor(s, 2);
    if (q == 0) WtQKV[(size_t)(1536 + n) * 512 + k] = f2bf(s);
  } else if (bid < 12320) {                   // ---- kg + kgo ----
    const int bg_ = bid - 12288;              // (b = bg_>>2, g = bg_&3)
    const int b = bg_ >> 2, g = bg_ & 3;
    const int gidx[4] = {0, 1365, 2730, 4095};
    const float* xr = &x[((size_t)b * SS + gidx[g]) * CC];
    if (t < 128) {
      float sv = bg[t];
      for (int c = 0; c < CC; c++) sv += xr[c] * Wg[c * 128 + t];
      kr[t] = sv;
      kg[bg_ * 128 + t] = sv;
    }
    __syncthreads();
    for (int c = t; c < 512; c += 256) {
      float sv = 0.f;
      for (int d = 0; d < 128; d++) sv += kr[d] * Wgo[d * 512 + c];
      kgo[bg_ * 512 + c] = sv;
    }
  } else {                                    // ---- bqg, 2 threads/output ----
    const int o = t >> 1, h = t & 1;
    float s = h ? 0.f : bg[o];
    const int c0 = h * 256;
    for (int c = 0; c < 256; c++) s += bq[c0 + c] * Wg[(size_t)(c0 + c) * 128 + o];
    s += __shfl_xor(s, 1);
    if (h == 0) bqkv[1536 + o] = s;
  }
}

// ---------------- bf16 MFMA GEMM, BK=64 single-buffer, XOR-swizzled LDS (r8 proven) ----
// C[M,N] = A[M,512] @ Wt[N,512]^T + bias. tile 128x128, 4 waves (2x2), wave 64x64.
// LDS rows 128B -> both-sides involution (rule 21): source chunk ^= row&7, reader ^= (row&7)<<4 B.
template<int OUT_BF16, int SWZ>
__global__ __launch_bounds__(256, 3) void gemm_kernel(
    const short* __restrict__ A,
    const short* __restrict__ Wt,
    const float* __restrict__ bias,
    void* __restrict__ Cp, int ldc, int nx)
{
  __shared__ short As[128 * 64];
  __shared__ short Bs[128 * 64];
  int id = blockIdx.x;
  if (SWZ) {                              // T1: contiguous tile chunk per XCD (grid%8==0)
    const int cpx = gridDim.x >> 3;
    id = (id & 7) * cpx + (id >> 3);
  }
  const int n0 = (id % nx) * 128;
  const int m0 = (id / nx) * 128;
  const int t = threadIdx.x;
  const int lane = t & 63, w = t >> 6;
  const int wm = (w >> 1) * 64, wn = (w & 1) * 64;
  const int lr = lane & 15;
  const int g8b = (lane >> 4) * 16;       // byte offset of k-frag (8 bf16)
  const int xorb = (lr & 7) << 4;         // reader swizzle (row&7)<<4 bytes

  const int srow = w * 8 + (lane >> 3);
  const int scol = (((lane & 7) ^ (lane >> 3)) << 4) >> 1;    // elems
  const short* Ag = A + (size_t)(m0 + srow) * 512 + scol;
  const short* Bg = Wt + (size_t)(n0 + srow) * 512 + scol;
  short* Al = &As[(w * 8) * 64];
  short* Bl = &Bs[(w * 8) * 64];

  f32x4 acc[4][4];
#pragma unroll
  for (int i = 0; i < 4; i++)
#pragma unroll
    for (int j = 0; j < 4; j++) acc[i][j] = (f32x4){0.f, 0.f, 0.f, 0.f};

  for (int k0 = 0; k0 < 512; k0 += 64) {
#pragma unroll
    for (int s = 0; s < 4; s++) {
      gload_lds16(Ag + k0 + s * (32 * 512), Al + s * (32 * 64));
      gload_lds16(Bg + k0 + s * (32 * 512), Bl + s * (32 * 64));
    }
    __syncthreads();                     // implicit vmcnt(0) drain
#pragma unroll
    for (int kk = 0; kk < 2; kk++) {
      bf16x8 af[4], bfr[4];
      const int ko = ((kk * 64 + g8b) ^ xorb) >> 1;   // swizzled elem offset in row
#pragma unroll
      for (int mt = 0; mt < 4; mt++) af[mt]  = *(bf16x8*)&As[(wm + mt * 16 + lr) * 64 + ko];
#pragma unroll
      for (int nt = 0; nt < 4; nt++) bfr[nt] = *(bf16x8*)&Bs[(wn + nt * 16 + lr) * 64 + ko];
#pragma unroll
      for (int mt = 0; mt < 4; mt++)
#pragma unroll
        for (int nt = 0; nt < 4; nt++)
          acc[mt][nt] = __builtin_amdgcn_mfma_f32_16x16x32_bf16(af[mt], bfr[nt], acc[mt][nt], 0, 0, 0);
    }
    __syncthreads();
  }

  const int cr = (lane >> 4) * 4;
#pragma unroll
  for (int nt = 0; nt < 4; nt++) {
    int col = n0 + wn + nt * 16 + lr;
    float bv = bias[col];
#pragma unroll
    for (int mt = 0; mt < 4; mt++) {
      int row = m0 + wm + mt * 16 + cr;
#pragma unroll
      for (int j = 0; j < 4; j++) {
        float v = acc[mt][nt][j] + bv;
        if (OUT_BF16) ((short*)Cp)[(size_t)(row + j) * ldc + col] = f2bf(v);
        else          ((float*)Cp)[(size_t)(row + j) * ldc + col] = v;
      }
    }
  }
}

// ---------------- fused windowed attention + combine (v5: split QK^T across wave pair) -
// Block = 4 waves, 2 windows (32 tokens). Wave (win,half) computes QK^T only over
// k in [half*256, half*256+256) (8 MFMAs); partial S exchanged via LDS at the first
// barrier (which also drains the async V stage). PV/col-half split unchanged.
__global__ __launch_bounds__(256, 4) void winattn_combine_kernel(
    const short* __restrict__ qkvb, const short* __restrict__ xb,
    const float* __restrict__ kg, const float* __restrict__ kgo,
    const float* __restrict__ bgo, const float* __restrict__ pavg,
    const float* __restrict__ pmax, const float* __restrict__ conv_w,
    short* __restrict__ y)
{
  __shared__ short vs[2][16][512];            // V then xl, row-linear, data swizzled
  __shared__ float4 ps[2][2][64];             // partial S per (win, half, lane)
  __shared__ float4 esm[32];
  __shared__ float gateb[32];
  const int t = threadIdx.x;
  const int lane = t & 63, w = t >> 6;
  const int t0b = blockIdx.x * 32;            // block token base
  const int bb = t0b >> 12;                   // batch
  const int win = w >> 1, half = w & 1;
  const int t0 = t0b + win * 16;              // window token base

  // ---- V stage: wave covers rows half*8..+7 of its window; chunk l -> l^(r&7) ----
  {
    const int rb = half * 8;
#pragma unroll
    for (int i = 0; i < 8; i++) {
      const int r = rb + i;
      const short* vrow = &qkvb[(size_t)(t0 + r) * QKVS + 1024];
      gload_lds16(vrow + ((lane ^ (r & 7)) << 3), &vs[win][r][0]);
    }
  }

  // ---- QK^T (swapped), HALF k-range per wave: [half*256, half*256+256) ----
  const int qrow = lane & 15;
  const int grp8 = (lane >> 4) * 8;
  const int krow = (lane >> 4) * 4;
  const int colo = lane & 15;

  const short* kqbase = &qkvb[(size_t)(t0 + qrow) * QKVS];
  const int kb0 = half * 256;
  f32x4 accA = (f32x4){0.f, 0.f, 0.f, 0.f};
  f32x4 accB = (f32x4){0.f, 0.f, 0.f, 0.f};
#pragma unroll
  for (int k0 = 0; k0 < 256; k0 += 64) {
    bf16x8 kf0 = *(const bf16x8*)&kqbase[512 + kb0 + k0 + grp8];
    bf16x8 qf0 = *(const bf16x8*)&kqbase[kb0 + k0 + grp8];
    bf16x8 kf1 = *(const bf16x8*)&kqbase[512 + kb0 + k0 + 32 + grp8];
    bf16x8 qf1 = *(const bf16x8*)&kqbase[kb0 + k0 + 32 + grp8];
    accA = __builtin_amdgcn_mfma_f32_16x16x32_bf16(kf0, qf0, accA, 0, 0, 0);
    accB = __builtin_amdgcn_mfma_f32_16x16x32_bf16(kf1, qf1, accB, 0, 0, 0);
  }
  f32x4 part = accA + accB;
  ps[win][half][lane] = (float4){part[0], part[1], part[2], part[3]};

  // ---- gattn scores + conv gate: wave w -> tokens w*8..w*8+7, 8 lanes per token ----
  {
    const int tl = w * 8 + (lane >> 3);       // block-local token
    const int sub = lane & 7;                 // 16-elem slice
    const short* qr = &qkvb[(size_t)(t0b + tl) * QKVS + 1536 + sub * 16];
    bf16x8 qv0 = *(const bf16x8*)&qr[0];
    bf16x8 qv1 = *(const bf16x8*)&qr[8];
    const float* kr = &kg[bb * 512 + sub * 16];
    float p[4];
#pragma unroll
    for (int g = 0; g < 4; g++) {
      float4 ka = *(const float4*)&kr[g * 128];
      float4 kbv = *(const float4*)&kr[g * 128 + 4];
      float4 kc = *(const float4*)&kr[g * 128 + 8];
      float4 kd = *(const float4*)&kr[g * 128 + 12];
      float s = bf2f(qv0[0]) * ka.x + bf2f(qv0[1]) * ka.y + bf2f(qv0[2]) * ka.z + bf2f(qv0[3]) * ka.w
              + bf2f(qv0[4]) * kbv.x + bf2f(qv0[5]) * kbv.y + bf2f(qv0[6]) * kbv.z + bf2f(qv0[7]) * kbv.w
              + bf2f(qv1[0]) * kc.x + bf2f(qv1[1]) * kc.y + bf2f(qv1[2]) * kc.z + bf2f(qv1[3]) * kc.w
              + bf2f(qv1[4]) * kd.x + bf2f(qv1[5]) * kd.y + bf2f(qv1[6]) * kd.z + bf2f(qv1[7]) * kd.w;
      p[g] = s;
    }
#pragma unroll
    for (int off = 1; off < 8; off <<= 1) {
#pragma unroll
      for (int g = 0; g < 4; g++) p[g] += __shfl_xor(p[g], off);
    }
    if (sub == 0) {
      const float gs = 0.08838834764831845f;  // 1/sqrt(128)
      float p0 = p[0] * gs, p1 = p[1] * gs, p2 = p[2] * gs, p3 = p[3] * gs;
      float mx = fmaxf(fmaxf(p0, p1), fmaxf(p2, p3));
      float e0 = __expf(p0 - mx), e1 = __expf(p1 - mx), e2 = __expf(p2 - mx), e3 = __expf(p3 - mx);
      float inv = 1.0f / (e0 + e1 + e2 + e3);
      esm[tl] = make_float4(e0 * inv, e1 * inv, e2 * inv, e3 * inv);
      int s = (t0b + tl) & 4095;
      float g = 0.f;
#pragma unroll
      for (int tk = 0; tk < 7; tk++) {
        int ss = s + tk - 3;
        if (ss >= 0 && ss < SS)
          g += conv_w[tk] * pavg[bb * SS + ss] + conv_w[7 + tk] * pmax[bb * SS + ss];
      }
      gateb[tl] = 1.0f / (1.0f + __expf(-g));
    }
  }

  __syncthreads();      // drains V gloads; publishes ps / esm / gateb

  // ---- combine partner partial + softmax over 16 keys ----
  const float4 oth = ps[win][half ^ 1][lane];
  const float scale = 0.04419417382415922f;   // 1/sqrt(512)
  float s0 = (part[0] + oth.x) * scale, s1 = (part[1] + oth.y) * scale;
  float s2 = (part[2] + oth.z) * scale, s3 = (part[3] + oth.w) * scale;
  float m = fmaxf(fmaxf(s0, s1), fmaxf(s2, s3));
  m = fmaxf(m, __shfl_xor(m, 16));
  m = fmaxf(m, __shfl_xor(m, 32));
  float e0 = __expf(s0 - m), e1 = __expf(s1 - m), e2 = __expf(s2 - m), e3 = __expf(s3 - m);
  float sum = e0 + e1 + e2 + e3;
  sum += __shfl_xor(sum, 16);
  sum += __shfl_xor(sum, 32);
  float inv = 1.0f / sum;
  s16x4 pa;
  pa[0] = f2bf(e0 * inv); pa[1] = f2bf(e1 * inv);
  pa[2] = f2bf(e2 * inv); pa[3] = f2bf(e3 * inv);

  // ---- PV: read V from LDS (swizzled), mfma, overwrite consumed subtile with xl ----
#pragma unroll
  for (int ct = 0; ct < 16; ct++) {
    const int cb = (half * 256 + ct * 16 + colo) * 2;   // byte offset in row
    s16x4 bf;
#pragma unroll
    for (int u = 0; u < 4; u++) {
      const int r = krow + u;
      bf[u] = vs[win][r][(cb ^ ((r & 7) << 4)) >> 1];
    }
    f32x4 d = pv_mfma(pa, bf, (f32x4){0.f, 0.f, 0.f, 0.f});
#pragma unroll
    for (int jj = 0; jj < 4; jj++) {
      const int r = krow + jj;                          // D row = q index
      vs[win][r][(cb ^ ((r & 7) << 4)) >> 1] = f2bf(d[jj]);
    }
  }
  __syncthreads();

  // ---- vectorized combine: thread -> (row r=t>>3, cols (t&7)*8 + 64*it) ----
  const int r = t >> 3;
  const int rowg = t0b + r;
  const int winr = r >> 4, rr = r & 15;
  const float4 e = esm[r];
  const float g = gateb[r];
  const float* kgr = &kgo[bb * 2048];
  const short* xrow = &xb[(size_t)rowg * CC];
  const short* xlrow = &vs[winr][rr][0];
  short* yrow = &y[(size_t)rowg * CC];
#pragma unroll
  for (int it = 0; it < 8; it++) {
    const int c = (t & 7) * 8 + it * 64;
    bf16x8 xv  = *(const bf16x8*)&xrow[c];
    bf16x8 xlv = *(const bf16x8*)&xlrow[((c * 2) ^ ((rr & 7) << 4)) >> 1];
    float4 k0a = *(const float4*)&kgr[c],        k0b = *(const float4*)&kgr[c + 4];
    float4 k1a = *(const float4*)&kgr[512 + c],  k1b = *(const float4*)&kgr[512 + c + 4];
    float4 k2a = *(const float4*)&kgr[1024 + c], k2b = *(const float4*)&kgr[1024 + c + 4];
    float4 k3a = *(const float4*)&kgr[1536 + c], k3b = *(const float4*)&kgr[1536 + c + 4];
    float4 ba  = *(const float4*)&bgo[c],        bbv = *(const float4*)&bgo[c + 4];
    float xg[8];
    xg[0] = e.x * k0a.x + e.y * k1a.x + e.z * k2a.x + e.w * k3a.x + ba.x;
    xg[1] = e.x * k0a.y + e.y * k1a.y + e.z * k2a.y + e.w * k3a.y + ba.y;
    xg[2] = e.x * k0a.z + e.y * k1a.z + e.z * k2a.z + e.w * k3a.z + ba.z;
    xg[3] = e.x * k0a.w + e.y * k1a.w + e.z * k2a.w + e.w * k3a.w + ba.w;
    xg[4] = e.x * k0b.x + e.y * k1b.x + e.z * k2b.x + e.w * k3b.x + bbv.x;
    xg[5] = e.x * k0b.y + e.y * k1b.y + e.z * k2b.y + e.w * k3b.y + bbv.y;
    xg[6] = e.x * k0b.z + e.y * k1b.z + e.z * k2b.z + e.w * k3b.z + bbv.z;
    xg[7] = e.x * k0b.w + e.y * k1b.w + e.z * k2b.w + e.w * k3b.w + bbv.w;
    bf16x8 ov;
#pragma unroll
    for (int u = 0; u < 8; u++)
      ov[u] = f2bf((bf2f(xv[u]) + bf2f(xlv[u]) + xg[u]) * g);
    *(bf16x8*)&yrow[c] = ov;
  }
}

// ---------------- launcher ----------------
extern "C" void kernel_launch(void* const* d_in, const int* in_sizes, int n_in,
                              void* d_out, int out_size, void* d_ws, size_t ws_size,
                              hipStream_t stream)
{
  const float* x     = (const float*)d_in[0];
  const float* Wq    = (const float*)d_in[1];
  const float* bq    = (const float*)d_in[2];
  const float* Wk    = (const float*)d_in[3];
  const float* bk    = (const float*)d_in[4];
  const float* Wv    = (const float*)d_in[5];
  const float* bv    = (const float*)d_in[6];
  const float* Wo    = (const float*)d_in[7];
  const float* bo    = (const float*)d_in[8];
  const float* Wg    = (const float*)d_in[9];
  const float* bg    = (const float*)d_in[10];
  const float* Wgo   = (const float*)d_in[11];
  const float* bgo   = (const float*)d_in[12];
  const float* convw = (const float*)d_in[13];
  float* out = (float*)d_out;

  char* ws = (char*)d_ws;
  size_t off = 0;
  auto alloc = [&](size_t bytes) -> void* {
    void* p = ws + off;
    off += (bytes + 255) & ~(size_t)255;
    return p;
  };
  short* xb    = (short*)alloc((size_t)NTOK * CC * 2);           // 33.5 MB
  short* qkvb  = (short*)alloc((size_t)NTOK * QKVS * 2);         // 109 MB
  short* WtQKV = (short*)alloc((size_t)QKVS * 512 * 2);          // [q|k|v|WqWg] rows
  short* WtO   = (short*)alloc((size_t)512 * 512 * 2);
  float* bqkv  = (float*)alloc(QKVS * 4);
  float* kg    = (float*)alloc(8 * 4 * 128 * 4);
  float* kgo   = (float*)alloc(8 * 4 * 512 * 4);
  float* pavg  = (float*)alloc((size_t)NTOK * 4);
  float* pmax  = (float*)alloc((size_t)NTOK * 4);
  short* ybuf  = (short*)alloc((size_t)NTOK * CC * 2);           // 33.5 MB (final y)

  // all front work: cast+pool | weight prep | fold | kg/kgo | bqg  (independent pieces)
  front_kernel<<<12321, 256, 0, stream>>>(x, Wq, Wk, Wv, Wo, Wg, bq, bk, bv, bg, Wgo,
                                          xb, pavg, pmax, WtQKV, WtO, bqkv, kg, kgo);

  // qkv|qg = x @ [Wq|Wk|Wv|WqWg] + [bq|bk|bv|bqg]  (M=32768, N=1664), nwg=3328
  gemm_kernel<1, 1><<<13 * 256, 256, 0, stream>>>(xb, WtQKV, bqkv, qkvb, QKVS, 13);

  // fused window-attention + global-attn combine + gate -> y (bf16)
  winattn_combine_kernel<<<NTOK / 32, 256, 0, stream>>>(qkvb, xb, kg, kgo, bgo,
                                                        pavg, pmax, convw, ybuf);

  // out = y @ Wo + bo  (M=32768, N=512, fp32 out), nwg=1024
  gemm_kernel<0, 1><<<4 * 256, 256, 0, stream>>>(ybuf, WtO, bo, out, CC, 4);
}

// Round 14
// 205.638 us; speedup vs baseline: 1.0622x; 1.0289x over previous
//
#include <hip/hip_runtime.h>
#include <hip/hip_bf16.h>

#define BB 8
#define SS 4096
#define CC 512
#define NTOK (BB*SS)   // 32768
#define QKVS 1664      // q(512) | k(512) | v(512) | qg(128)

typedef __attribute__((ext_vector_type(8))) short bf16x8;
typedef __attribute__((ext_vector_type(4))) float f32x4;
typedef __attribute__((ext_vector_type(4))) short s16x4;

__device__ __forceinline__ float bf2f(short s) {
  return __uint_as_float(((unsigned)(unsigned short)s) << 16);
}
__device__ __forceinline__ short f2bf(float f) {
  __hip_bfloat16 h = __float2bfloat16(f);
  return *reinterpret_cast<short*>(&h);
}

__device__ __forceinline__ f32x4 pv_mfma(s16x4 a, s16x4 b, f32x4 c) {
#if __has_builtin(__builtin_amdgcn_mfma_f32_16x16x16bf16_1k)
  return __builtin_amdgcn_mfma_f32_16x16x16bf16_1k(a, b, c, 0, 0, 0);
#else
  f32x4 d;
  asm volatile("v_mfma_f32_16x16x16_bf16 %0, %1, %2, %3\n\ts_nop 7\n\ts_nop 7"
               : "=v"(d) : "v"(a), "v"(b), "v"(c));
  return d;
#endif
}

// async global -> LDS, 16B per lane; LDS dest is wave-uniform base + lane*16
__device__ __forceinline__ void gload_lds16(const short* g, short* l) {
  __builtin_amdgcn_global_load_lds(
      (const __attribute__((address_space(1))) unsigned int*)g,
      (__attribute__((address_space(3))) unsigned int*)l, 16, 0, 0);
}

// ---------------- front: ONE launch, all independent pieces ----------------
// blocks [0,8192):      cast x->bf16 + channel pool (4 tokens/block)
// blocks [8192,8448):   LDS-tiled weight transpose (4 matrices x 64 tiles of 64x64)
// blocks [8448,9472):   WqWg fold -> WtQKV rows [1536,1664), 4 threads/output
// blocks [9472,9504):   kg+kgo per (b,g)
// block  9504:          bqg -> bqkv[1536..]
// blocks [9505,9511):   bqkv concat (qkv biases)
__global__ __launch_bounds__(256) void front_kernel(
    const float* __restrict__ x,
    const float* __restrict__ Wq, const float* __restrict__ Wk, const float* __restrict__ Wv,
    const float* __restrict__ Wo, const float* __restrict__ Wg,
    const float* __restrict__ bq, const float* __restrict__ bk, const float* __restrict__ bv,
    const float* __restrict__ bg, const float* __restrict__ Wgo,
    short* __restrict__ xb, float* __restrict__ pavg, float* __restrict__ pmax,
    short* __restrict__ WtQKV, short* __restrict__ WtO, float* __restrict__ bqkv,
    float* __restrict__ kg, float* __restrict__ kgo)
{
  __shared__ short tile[64][72];              // transpose tile (padded); kr aliases fine
  __shared__ float kr[128];
  const int t = threadIdx.x;
  const int bid = blockIdx.x;

  if (bid < 8192) {                           // ---- cast + pool ----
    int tok = bid * 4 + (t >> 6);
    int lane = t & 63;
    const float* xr = &x[(size_t)tok * CC];
    float4 a = *(const float4*)&xr[lane * 4];
    float4 b = *(const float4*)&xr[256 + lane * 4];
    s16x4 oa, ob;
    oa[0] = f2bf(a.x); oa[1] = f2bf(a.y); oa[2] = f2bf(a.z); oa[3] = f2bf(a.w);
    ob[0] = f2bf(b.x); ob[1] = f2bf(b.y); ob[2] = f2bf(b.z); ob[3] = f2bf(b.w);
    *(s16x4*)&xb[(size_t)tok * CC + lane * 4] = oa;
    *(s16x4*)&xb[(size_t)tok * CC + 256 + lane * 4] = ob;
    float s = (a.x + a.y) + (a.z + a.w) + (b.x + b.y) + (b.z + b.w);
    float m = fmaxf(fmaxf(fmaxf(a.x, a.y), fmaxf(a.z, a.w)),
                    fmaxf(fmaxf(b.x, b.y), fmaxf(b.z, b.w)));
#pragma unroll
    for (int off = 32; off; off >>= 1) {
      s += __shfl_down(s, off);
      m = fmaxf(m, __shfl_down(m, off));
    }
    if (lane == 0) { pavg[tok] = s * (1.0f / CC); pmax[tok] = m; }
  } else if (bid < 8448) {                    // ---- LDS-tiled transpose ----
    const int tt = bid - 8192;
    const int sel = tt >> 6;                  // 0=Wq 1=Wk 2=Wv 3=Wo
    const int tn = (tt & 63) >> 3, tk = (tt & 63) & 7;
    const int n0 = tn * 64, k0 = tk * 64;
    const float* W = (sel == 0) ? Wq : (sel == 1) ? Wk : (sel == 2) ? Wv : Wo;
    short* dst = (sel < 3) ? (WtQKV + (size_t)sel * 512 * 512) : WtO;
    // load: thread (r=t>>2, seg=t&3) reads 16 consecutive floats of row k0+r
    {
      const int r = t >> 2, cg = (t & 3) * 16;
      const float* src = &W[(size_t)(k0 + r) * 512 + n0 + cg];
      short* lrow = &tile[r][cg];
#pragma unroll
      for (int j = 0; j < 16; j += 4) {
        float4 v = *(const float4*)&src[j];
        lrow[j + 0] = f2bf(v.x); lrow[j + 1] = f2bf(v.y);
        lrow[j + 2] = f2bf(v.z); lrow[j + 3] = f2bf(v.w);
      }
    }
    __syncthreads();
    // store: thread (n=t>>2, ks=t&3) writes 16 consecutive k of output row n0+n
    {
      const int n = t >> 2, ks = (t & 3) * 16;
      bf16x8 o0, o1;
#pragma unroll
      for (int j = 0; j < 8; j++) o0[j] = tile[ks + j][n];
#pragma unroll
      for (int j = 0; j < 8; j++) o1[j] = tile[ks + 8 + j][n];
      short* orow = &dst[(size_t)(n0 + n) * 512 + k0 + ks];
      *(bf16x8*)&orow[0] = o0;
      *(bf16x8*)&orow[8] = o1;
    }
  } else if (bid < 9472) {                    // ---- WqWg fold, 4 threads/output ----
    const int o = ((bid - 8448) * 256 + t) >> 2;
    const int q = t & 3;
    const int n = o >> 9, k = o & 511;
    const float* wqr = &Wq[(size_t)k * 512];
    float s = 0.f;
    const int c0 = q * 128;
    for (int c = 0; c < 128; c++) s += wqr[c0 + c] * Wg[(size_t)(c0 + c) * 128 + n];
    s += __shfl_xor(s, 1);
    s += __shfl_xor(s, 2);
    if (q == 0) WtQKV[(size_t)(1536 + n) * 512 + k] = f2bf(s);
  } else if (bid < 9504) {                    // ---- kg + kgo ----
    const int bg_ = bid - 9472;               // (b = bg_>>2, g = bg_&3)
    const int b = bg_ >> 2, g = bg_ & 3;
    const int gidx[4] = {0, 1365, 2730, 4095};
    const float* xr = &x[((size_t)b * SS + gidx[g]) * CC];
    if (t < 128) {
      float sv = bg[t];
      for (int c = 0; c < CC; c++) sv += xr[c] * Wg[c * 128 + t];
      kr[t] = sv;
      kg[bg_ * 128 + t] = sv;
    }
    __syncthreads();
    for (int c = t; c < 512; c += 256) {
      float sv = 0.f;
      for (int d = 0; d < 128; d++) sv += kr[d] * Wgo[d * 512 + c];
      kgo[bg_ * 512 + c] = sv;
    }
  } else if (bid == 9504) {                   // ---- bqg, 2 threads/output ----
    const int o = t >> 1, h = t & 1;
    float s = h ? 0.f : bg[o];
    const int c0 = h * 256;
    for (int c = 0; c < 256; c++) s += bq[c0 + c] * Wg[(size_t)(c0 + c) * 128 + o];
    s += __shfl_xor(s, 1);
    if (h == 0) bqkv[1536 + o] = s;
  } else {                                    // ---- bqkv concat ----
    int i = (bid - 9505) * 256 + t;
    if (i < 1536)
      bqkv[i] = (i < 512) ? bq[i] : (i < 1024) ? bk[i - 512] : bv[i - 1024];
  }
}

// ---------------- bf16 MFMA GEMM, BK=64 single-buffer, XOR-swizzled LDS (r8 proven) ----
// C[M,N] = A[M,512] @ Wt[N,512]^T + bias. tile 128x128, 4 waves (2x2), wave 64x64.
// LDS rows 128B -> both-sides involution (rule 21): source chunk ^= row&7, reader ^= (row&7)<<4 B.
template<int OUT_BF16, int SWZ>
__global__ __launch_bounds__(256, 3) void gemm_kernel(
    const short* __restrict__ A,
    const short* __restrict__ Wt,
    const float* __restrict__ bias,
    void* __restrict__ Cp, int ldc, int nx)
{
  __shared__ short As[128 * 64];
  __shared__ short Bs[128 * 64];
  int id = blockIdx.x;
  if (SWZ) {                              // T1: contiguous tile chunk per XCD (grid%8==0)
    const int cpx = gridDim.x >> 3;
    id = (id & 7) * cpx + (id >> 3);
  }
  const int n0 = (id % nx) * 128;
  const int m0 = (id / nx) * 128;
  const int t = threadIdx.x;
  const int lane = t & 63, w = t >> 6;
  const int wm = (w >> 1) * 64, wn = (w & 1) * 64;
  const int lr = lane & 15;
  const int g8b = (lane >> 4) * 16;       // byte offset of k-frag (8 bf16)
  const int xorb = (lr & 7) << 4;         // reader swizzle (row&7)<<4 bytes

  const int srow = w * 8 + (lane >> 3);
  const int scol = (((lane & 7) ^ (lane >> 3)) << 4) >> 1;    // elems
  const short* Ag = A + (size_t)(m0 + srow) * 512 + scol;
  const short* Bg = Wt + (size_t)(n0 + srow) * 512 + scol;
  short* Al = &As[(w * 8) * 64];
  short* Bl = &Bs[(w * 8) * 64];

  f32x4 acc[4][4];
#pragma unroll
  for (int i = 0; i < 4; i++)
#pragma unroll
    for (int j = 0; j < 4; j++) acc[i][j] = (f32x4){0.f, 0.f, 0.f, 0.f};

  for (int k0 = 0; k0 < 512; k0 += 64) {
#pragma unroll
    for (int s = 0; s < 4; s++) {
      gload_lds16(Ag + k0 + s * (32 * 512), Al + s * (32 * 64));
      gload_lds16(Bg + k0 + s * (32 * 512), Bl + s * (32 * 64));
    }
    __syncthreads();                     // implicit vmcnt(0) drain
#pragma unroll
    for (int kk = 0; kk < 2; kk++) {
      bf16x8 af[4], bfr[4];
      const int ko = ((kk * 64 + g8b) ^ xorb) >> 1;   // swizzled elem offset in row
#pragma unroll
      for (int mt = 0; mt < 4; mt++) af[mt]  = *(bf16x8*)&As[(wm + mt * 16 + lr) * 64 + ko];
#pragma unroll
      for (int nt = 0; nt < 4; nt++) bfr[nt] = *(bf16x8*)&Bs[(wn + nt * 16 + lr) * 64 + ko];
#pragma unroll
      for (int mt = 0; mt < 4; mt++)
#pragma unroll
        for (int nt = 0; nt < 4; nt++)
          acc[mt][nt] = __builtin_amdgcn_mfma_f32_16x16x32_bf16(af[mt], bfr[nt], acc[mt][nt], 0, 0, 0);
    }
    __syncthreads();
  }

  const int cr = (lane >> 4) * 4;
#pragma unroll
  for (int nt = 0; nt < 4; nt++) {
    int col = n0 + wn + nt * 16 + lr;
    float bv = bias[col];
#pragma unroll
    for (int mt = 0; mt < 4; mt++) {
      int row = m0 + wm + mt * 16 + cr;
#pragma unroll
      for (int j = 0; j < 4; j++) {
        float v = acc[mt][nt][j] + bv;
        if (OUT_BF16) ((short*)Cp)[(size_t)(row + j) * ldc + col] = f2bf(v);
        else          ((float*)Cp)[(size_t)(row + j) * ldc + col] = v;
      }
    }
  }
}

// ---------------- fused windowed attention + combine (v5: split QK^T across wave pair) -
__global__ __launch_bounds__(256, 4) void winattn_combine_kernel(
    const short* __restrict__ qkvb, const short* __restrict__ xb,
    const float* __restrict__ kg, const float* __restrict__ kgo,
    const float* __restrict__ bgo, const float* __restrict__ pavg,
    const float* __restrict__ pmax, const float* __restrict__ conv_w,
    short* __restrict__ y)
{
  __shared__ short vs[2][16][512];            // V then xl, row-linear, data swizzled
  __shared__ float4 ps[2][2][64];             // partial S per (win, half, lane)
  __shared__ float4 esm[32];
  __shared__ float gateb[32];
  const int t = threadIdx.x;
  const int lane = t & 63, w = t >> 6;
  const int t0b = blockIdx.x * 32;            // block token base
  const int bb = t0b >> 12;                   // batch
  const int win = w >> 1, half = w & 1;
  const int t0 = t0b + win * 16;              // window token base

  // ---- V stage: wave covers rows half*8..+7 of its window; chunk l -> l^(r&7) ----
  {
    const int rb = half * 8;
#pragma unroll
    for (int i = 0; i < 8; i++) {
      const int r = rb + i;
      const short* vrow = &qkvb[(size_t)(t0 + r) * QKVS + 1024];
      gload_lds16(vrow + ((lane ^ (r & 7)) << 3), &vs[win][r][0]);
    }
  }

  // ---- QK^T (swapped), HALF k-range per wave: [half*256, half*256+256) ----
  const int qrow = lane & 15;
  const int grp8 = (lane >> 4) * 8;
  const int krow = (lane >> 4) * 4;
  const int colo = lane & 15;

  const short* kqbase = &qkvb[(size_t)(t0 + qrow) * QKVS];
  const int kb0 = half * 256;
  f32x4 accA = (f32x4){0.f, 0.f, 0.f, 0.f};
  f32x4 accB = (f32x4){0.f, 0.f, 0.f, 0.f};
#pragma unroll
  for (int k0 = 0; k0 < 256; k0 += 64) {
    bf16x8 kf0 = *(const bf16x8*)&kqbase[512 + kb0 + k0 + grp8];
    bf16x8 qf0 = *(const bf16x8*)&kqbase[kb0 + k0 + grp8];
    bf16x8 kf1 = *(const bf16x8*)&kqbase[512 + kb0 + k0 + 32 + grp8];
    bf16x8 qf1 = *(const bf16x8*)&kqbase[kb0 + k0 + 32 + grp8];
    accA = __builtin_amdgcn_mfma_f32_16x16x32_bf16(kf0, qf0, accA, 0, 0, 0);
    accB = __builtin_amdgcn_mfma_f32_16x16x32_bf16(kf1, qf1, accB, 0, 0, 0);
  }
  f32x4 part = accA + accB;
  ps[win][half][lane] = (float4){part[0], part[1], part[2], part[3]};

  // ---- gattn scores + conv gate: wave w -> tokens w*8..w*8+7, 8 lanes per token ----
  {
    const int tl = w * 8 + (lane >> 3);       // block-local token
    const int sub = lane & 7;                 // 16-elem slice
    const short* qr = &qkvb[(size_t)(t0b + tl) * QKVS + 1536 + sub * 16];
    bf16x8 qv0 = *(const bf16x8*)&qr[0];
    bf16x8 qv1 = *(const bf16x8*)&qr[8];
    const float* kr = &kg[bb * 512 + sub * 16];
    float p[4];
#pragma unroll
    for (int g = 0; g < 4; g++) {
      float4 ka = *(const float4*)&kr[g * 128];
      float4 kbv = *(const float4*)&kr[g * 128 + 4];
      float4 kc = *(const float4*)&kr[g * 128 + 8];
      float4 kd = *(const float4*)&kr[g * 128 + 12];
      float s = bf2f(qv0[0]) * ka.x + bf2f(qv0[1]) * ka.y + bf2f(qv0[2]) * ka.z + bf2f(qv0[3]) * ka.w
              + bf2f(qv0[4]) * kbv.x + bf2f(qv0[5]) * kbv.y + bf2f(qv0[6]) * kbv.z + bf2f(qv0[7]) * kbv.w
              + bf2f(qv1[0]) * kc.x + bf2f(qv1[1]) * kc.y + bf2f(qv1[2]) * kc.z + bf2f(qv1[3]) * kc.w
              + bf2f(qv1[4]) * kd.x + bf2f(qv1[5]) * kd.y + bf2f(qv1[6]) * kd.z + bf2f(qv1[7]) * kd.w;
      p[g] = s;
    }
#pragma unroll
    for (int off = 1; off < 8; off <<= 1) {
#pragma unroll
      for (int g = 0; g < 4; g++) p[g] += __shfl_xor(p[g], off);
    }
    if (sub == 0) {
      const float gs = 0.08838834764831845f;  // 1/sqrt(128)
      float p0 = p[0] * gs, p1 = p[1] * gs, p2 = p[2] * gs, p3 = p[3] * gs;
      float mx = fmaxf(fmaxf(p0, p1), fmaxf(p2, p3));
      float e0 = __expf(p0 - mx), e1 = __expf(p1 - mx), e2 = __expf(p2 - mx), e3 = __expf(p3 - mx);
      float inv = 1.0f / (e0 + e1 + e2 + e3);
      esm[tl] = make_float4(e0 * inv, e1 * inv, e2 * inv, e3 * inv);
      int s = (t0b + tl) & 4095;
      float g = 0.f;
#pragma unroll
      for (int tk = 0; tk < 7; tk++) {
        int ss = s + tk - 3;
        if (ss >= 0 && ss < SS)
          g += conv_w[tk] * pavg[bb * SS + ss] + conv_w[7 + tk] * pmax[bb * SS + ss];
      }
      gateb[tl] = 1.0f / (1.0f + __expf(-g));
    }
  }

  __syncthreads();      // drains V gloads; publishes ps / esm / gateb

  // ---- combine partner partial + softmax over 16 keys ----
  const float4 oth = ps[win][half ^ 1][lane];
  const float scale = 0.04419417382415922f;   // 1/sqrt(512)
  float s0 = (part[0] + oth.x) * scale, s1 = (part[1] + oth.y) * scale;
  float s2 = (part[2] + oth.z) * scale, s3 = (part[3] + oth.w) * scale;
  float m = fmaxf(fmaxf(s0, s1), fmaxf(s2, s3));
  m = fmaxf(m, __shfl_xor(m, 16));
  m = fmaxf(m, __shfl_xor(m, 32));
  float e0 = __expf(s0 - m), e1 = __expf(s1 - m), e2 = __expf(s2 - m), e3 = __expf(s3 - m);
  float sum = e0 + e1 + e2 + e3;
  sum += __shfl_xor(sum, 16);
  sum += __shfl_xor(sum, 32);
  float inv = 1.0f / sum;
  s16x4 pa;
  pa[0] = f2bf(e0 * inv); pa[1] = f2bf(e1 * inv);
  pa[2] = f2bf(e2 * inv); pa[3] = f2bf(e3 * inv);

  // ---- PV: read V from LDS (swizzled), mfma, overwrite consumed subtile with xl ----
#pragma unroll
  for (int ct = 0; ct < 16; ct++) {
    const int cb = (half * 256 + ct * 16 + colo) * 2;   // byte offset in row
    s16x4 bf;
#pragma unroll
    for (int u = 0; u < 4; u++) {
      const int r = krow + u;
      bf[u] = vs[win][r][(cb ^ ((r & 7) << 4)) >> 1];
    }
    f32x4 d = pv_mfma(pa, bf, (f32x4){0.f, 0.f, 0.f, 0.f});
#pragma unroll
    for (int jj = 0; jj < 4; jj++) {
      const int r = krow + jj;                          // D row = q index
      vs[win][r][(cb ^ ((r & 7) << 4)) >> 1] = f2bf(d[jj]);
    }
  }
  __syncthreads();

  // ---- vectorized combine: thread -> (row r=t>>3, cols (t&7)*8 + 64*it) ----
  const int r = t >> 3;
  const int rowg = t0b + r;
  const int winr = r >> 4, rr = r & 15;
  const float4 e = esm[r];
  const float g = gateb[r];
  const float* kgr = &kgo[bb * 2048];
  const short* xrow = &xb[(size_t)rowg * CC];
  const short* xlrow = &vs[winr][rr][0];
  short* yrow = &y[(size_t)rowg * CC];
#pragma unroll
  for (int it = 0; it < 8; it++) {
    const int c = (t & 7) * 8 + it * 64;
    bf16x8 xv  = *(const bf16x8*)&xrow[c];
    bf16x8 xlv = *(const bf16x8*)&xlrow[((c * 2) ^ ((rr & 7) << 4)) >> 1];
    float4 k0a = *(const float4*)&kgr[c],        k0b = *(const float4*)&kgr[c + 4];
    float4 k1a = *(const float4*)&kgr[512 + c],  k1b = *(const float4*)&kgr[512 + c + 4];
    float4 k2a = *(const float4*)&kgr[1024 + c], k2b = *(const float4*)&kgr[1024 + c + 4];
    float4 k3a = *(const float4*)&kgr[1536 + c], k3b = *(const float4*)&kgr[1536 + c + 4];
    float4 ba  = *(const float4*)&bgo[c],        bbv = *(const float4*)&bgo[c + 4];
    float xg[8];
    xg[0] = e.x * k0a.x + e.y * k1a.x + e.z * k2a.x + e.w * k3a.x + ba.x;
    xg[1] = e.x * k0a.y + e.y * k1a.y + e.z * k2a.y + e.w * k3a.y + ba.y;
    xg[2] = e.x * k0a.z + e.y * k1a.z + e.z * k2a.z + e.w * k3a.z + ba.z;
    xg[3] = e.x * k0a.w + e.y * k1a.w + e.z * k2a.w + e.w * k3a.w + ba.w;
    xg[4] = e.x * k0b.x + e.y * k1b.x + e.z * k2b.x + e.w * k3b.x + bbv.x;
    xg[5] = e.x * k0b.y + e.y * k1b.y + e.z * k2b.y + e.w * k3b.y + bbv.y;
    xg[6] = e.x * k0b.z + e.y * k1b.z + e.z * k2b.z + e.w * k3b.z + bbv.z;
    xg[7] = e.x * k0b.w + e.y * k1b.w + e.z * k2b.w + e.w * k3b.w + bbv.w;
    bf16x8 ov;
#pragma unroll
    for (int u = 0; u < 8; u++)
      ov[u] = f2bf((bf2f(xv[u]) + bf2f(xlv[u]) + xg[u]) * g);
    *(bf16x8*)&yrow[c] = ov;
  }
}

// ---------------- launcher ----------------
extern "C" void kernel_launch(void* const* d_in, const int* in_sizes, int n_in,
                              void* d_out, int out_size, void* d_ws, size_t ws_size,
                              hipStream_t stream)
{
  const float* x     = (const float*)d_in[0];
  const float* Wq    = (const float*)d_in[1];
  const float* bq    = (const float*)d_in[2];
  const float* Wk    = (const float*)d_in[3];
  const float* bk    = (const float*)d_in[4];
  const float* Wv    = (const float*)d_in[5];
  const float* bv    = (const float*)d_in[6];
  const float* Wo    = (const float*)d_in[7];
  const float* bo    = (const float*)d_in[8];
  const float* Wg    = (const float*)d_in[9];
  const float* bg    = (const float*)d_in[10];
  const float* Wgo   = (const float*)d_in[11];
  const float* bgo   = (const float*)d_in[12];
  const float* convw = (const float*)d_in[13];
  float* out = (float*)d_out;

  char* ws = (char*)d_ws;
  size_t off = 0;
  auto alloc = [&](size_t bytes) -> void* {
    void* p = ws + off;
    off += (bytes + 255) & ~(size_t)255;
    return p;
  };
  short* xb    = (short*)alloc((size_t)NTOK * CC * 2);           // 33.5 MB
  short* qkvb  = (short*)alloc((size_t)NTOK * QKVS * 2);         // 109 MB
  short* WtQKV = (short*)alloc((size_t)QKVS * 512 * 2);          // [q|k|v|WqWg] rows
  short* WtO   = (short*)alloc((size_t)512 * 512 * 2);
  float* bqkv  = (float*)alloc(QKVS * 4);
  float* kg    = (float*)alloc(8 * 4 * 128 * 4);
  float* kgo   = (float*)alloc(8 * 4 * 512 * 4);
  float* pavg  = (float*)alloc((size_t)NTOK * 4);
  float* pmax  = (float*)alloc((size_t)NTOK * 4);
  short* ybuf  = (short*)alloc((size_t)NTOK * CC * 2);           // 33.5 MB (final y)

  // all front work in one launch (independent pieces; transpose now LDS-tiled)
  front_kernel<<<9511, 256, 0, stream>>>(x, Wq, Wk, Wv, Wo, Wg, bq, bk, bv, bg, Wgo,
                                         xb, pavg, pmax, WtQKV, WtO, bqkv, kg, kgo);

  // qkv|qg = x @ [Wq|Wk|Wv|WqWg] + [bq|bk|bv|bqg]  (M=32768, N=1664), nwg=3328
  gemm_kernel<1, 1><<<13 * 256, 256, 0, stream>>>(xb, WtQKV, bqkv, qkvb, QKVS, 13);

  // fused window-attention + global-attn combine + gate -> y (bf16)
  winattn_combine_kernel<<<NTOK / 32, 256, 0, stream>>>(qkvb, xb, kg, kgo, bgo,
                                                        pavg, pmax, convw, ybuf);

  // out = y @ Wo + bo  (M=32768, N=512, fp32 out), nwg=1024
  gemm_kernel<0, 1><<<4 * 256, 256, 0, stream>>>(ybuf, WtO, bo, out, CC, 4);
}

// Round 15
// 173.854 us; speedup vs baseline: 1.2564x; 1.1828x over previous
//
#include <hip/hip_runtime.h>
#include <hip/hip_bf16.h>

#define BB 8
#define SS 4096
#define CC 512
#define NTOK (BB*SS)   // 32768
#define QKVS 1664      // q(512) | k(512) | v(512) | qg(128)

typedef __attribute__((ext_vector_type(8))) short bf16x8;
typedef __attribute__((ext_vector_type(4))) float f32x4;
typedef __attribute__((ext_vector_type(4))) short s16x4;

__device__ __forceinline__ float bf2f(short s) {
  return __uint_as_float(((unsigned)(unsigned short)s) << 16);
}
__device__ __forceinline__ short f2bf(float f) {
  __hip_bfloat16 h = __float2bfloat16(f);
  return *reinterpret_cast<short*>(&h);
}

__device__ __forceinline__ f32x4 pv_mfma(s16x4 a, s16x4 b, f32x4 c) {
#if __has_builtin(__builtin_amdgcn_mfma_f32_16x16x16bf16_1k)
  return __builtin_amdgcn_mfma_f32_16x16x16bf16_1k(a, b, c, 0, 0, 0);
#else
  f32x4 d;
  asm volatile("v_mfma_f32_16x16x16_bf16 %0, %1, %2, %3\n\ts_nop 7\n\ts_nop 7"
               : "=v"(d) : "v"(a), "v"(b), "v"(c));
  return d;
#endif
}

// async global -> LDS, 16B per lane; LDS dest is wave-uniform base + lane*16
__device__ __forceinline__ void gload_lds16(const short* g, short* l) {
  __builtin_amdgcn_global_load_lds(
      (const __attribute__((address_space(1))) unsigned int*)g,
      (__attribute__((address_space(3))) unsigned int*)l, 16, 0, 0);
}

// ---------------- front: ONE launch, all independent pieces ----------------
// blocks [0,8192):      cast x->bf16 + channel pool (4 tokens/block)
// blocks [8192,8448):   LDS-tiled weight transpose (4 matrices x 64 tiles of 64x64)
// blocks [8448,8576):   WqWg fold, COALESCED: block b -> k rows 4b..4b+3, thread n<128
// blocks [8576,8608):   kg+kgo per (b,g)
// block  8608:          bqg -> bqkv[1536..]
// blocks [8609,8615):   bqkv concat (qkv biases)
__global__ __launch_bounds__(256) void front_kernel(
    const float* __restrict__ x,
    const float* __restrict__ Wq, const float* __restrict__ Wk, const float* __restrict__ Wv,
    const float* __restrict__ Wo, const float* __restrict__ Wg,
    const float* __restrict__ bq, const float* __restrict__ bk, const float* __restrict__ bv,
    const float* __restrict__ bg, const float* __restrict__ Wgo,
    short* __restrict__ xb, float* __restrict__ pavg, float* __restrict__ pmax,
    short* __restrict__ WtQKV, short* __restrict__ WtO, float* __restrict__ bqkv,
    float* __restrict__ kg, float* __restrict__ kgo)
{
  __shared__ short tile[64][72];              // transpose tile; fold reuses as fp32[2048]
  __shared__ float kr[128];
  const int t = threadIdx.x;
  const int bid = blockIdx.x;

  if (bid < 8192) {                           // ---- cast + pool ----
    int tok = bid * 4 + (t >> 6);
    int lane = t & 63;
    const float* xr = &x[(size_t)tok * CC];
    float4 a = *(const float4*)&xr[lane * 4];
    float4 b = *(const float4*)&xr[256 + lane * 4];
    s16x4 oa, ob;
    oa[0] = f2bf(a.x); oa[1] = f2bf(a.y); oa[2] = f2bf(a.z); oa[3] = f2bf(a.w);
    ob[0] = f2bf(b.x); ob[1] = f2bf(b.y); ob[2] = f2bf(b.z); ob[3] = f2bf(b.w);
    *(s16x4*)&xb[(size_t)tok * CC + lane * 4] = oa;
    *(s16x4*)&xb[(size_t)tok * CC + 256 + lane * 4] = ob;
    float s = (a.x + a.y) + (a.z + a.w) + (b.x + b.y) + (b.z + b.w);
    float m = fmaxf(fmaxf(fmaxf(a.x, a.y), fmaxf(a.z, a.w)),
                    fmaxf(fmaxf(b.x, b.y), fmaxf(b.z, b.w)));
#pragma unroll
    for (int off = 32; off; off >>= 1) {
      s += __shfl_down(s, off);
      m = fmaxf(m, __shfl_down(m, off));
    }
    if (lane == 0) { pavg[tok] = s * (1.0f / CC); pmax[tok] = m; }
  } else if (bid < 8448) {                    // ---- LDS-tiled transpose ----
    const int tt = bid - 8192;
    const int sel = tt >> 6;                  // 0=Wq 1=Wk 2=Wv 3=Wo
    const int tn = (tt & 63) >> 3, tk = (tt & 63) & 7;
    const int n0 = tn * 64, k0 = tk * 64;
    const float* W = (sel == 0) ? Wq : (sel == 1) ? Wk : (sel == 2) ? Wv : Wo;
    short* dst = (sel < 3) ? (WtQKV + (size_t)sel * 512 * 512) : WtO;
    {
      const int r = t >> 2, cg = (t & 3) * 16;
      const float* src = &W[(size_t)(k0 + r) * 512 + n0 + cg];
      short* lrow = &tile[r][cg];
#pragma unroll
      for (int j = 0; j < 16; j += 4) {
        float4 v = *(const float4*)&src[j];
        lrow[j + 0] = f2bf(v.x); lrow[j + 1] = f2bf(v.y);
        lrow[j + 2] = f2bf(v.z); lrow[j + 3] = f2bf(v.w);
      }
    }
    __syncthreads();
    {
      const int n = t >> 2, ks = (t & 3) * 16;
      bf16x8 o0, o1;
#pragma unroll
      for (int j = 0; j < 8; j++) o0[j] = tile[ks + j][n];
#pragma unroll
      for (int j = 0; j < 8; j++) o1[j] = tile[ks + 8 + j][n];
      short* orow = &dst[(size_t)(n0 + n) * 512 + k0 + ks];
      *(bf16x8*)&orow[0] = o0;
      *(bf16x8*)&orow[8] = o1;
    }
  } else if (bid < 8576) {                    // ---- WqWg fold, coalesced ----
    // block fb: k rows 4fb..4fb+3; stage them in LDS (contiguous 2048 floats),
    // thread n<128: for c, g=Wg[c*128+n] (coalesced), acc[j]+=wqs[j*512+c]*g.
    const int fb = bid - 8448;
    const int k0 = fb * 4;
    float* wqs = (float*)&tile[0][0];         // 2048 floats = 8192B <= 9216B
    {
      const float* src = &Wq[(size_t)k0 * 512 + t * 8];
      float4 v0 = *(const float4*)&src[0];
      float4 v1 = *(const float4*)&src[4];
      *(float4*)&wqs[t * 8] = v0;
      *(float4*)&wqs[t * 8 + 4] = v1;
    }
    __syncthreads();
    if (t < 128) {
      const int n = t;
      float a0 = 0.f, a1 = 0.f, a2 = 0.f, a3 = 0.f;
      for (int c = 0; c < 512; c++) {
        float g = Wg[(size_t)c * 128 + n];
        a0 += wqs[c] * g;
        a1 += wqs[512 + c] * g;
        a2 += wqs[1024 + c] * g;
        a3 += wqs[1536 + c] * g;
      }
      s16x4 ov;
      ov[0] = f2bf(a0); ov[1] = f2bf(a1); ov[2] = f2bf(a2); ov[3] = f2bf(a3);
      *(s16x4*)&WtQKV[(size_t)(1536 + n) * 512 + k0] = ov;
    }
  } else if (bid < 8608) {                    // ---- kg + kgo ----
    const int bg_ = bid - 8576;               // (b = bg_>>2, g = bg_&3)
    const int b = bg_ >> 2, g = bg_ & 3;
    const int gidx[4] = {0, 1365, 2730, 4095};
    const float* xr = &x[((size_t)b * SS + gidx[g]) * CC];
    if (t < 128) {
      float sv = bg[t];
      for (int c = 0; c < CC; c++) sv += xr[c] * Wg[c * 128 + t];
      kr[t] = sv;
      kg[bg_ * 128 + t] = sv;
    }
    __syncthreads();
    for (int c = t; c < 512; c += 256) {
      float sv = 0.f;
      for (int d = 0; d < 128; d++) sv += kr[d] * Wgo[d * 512 + c];
      kgo[bg_ * 512 + c] = sv;
    }
  } else if (bid == 8608) {                   // ---- bqg, 2 threads/output ----
    const int o = t >> 1, h = t & 1;
    float s = h ? 0.f : bg[o];
    const int c0 = h * 256;
    for (int c = 0; c < 256; c++) s += bq[c0 + c] * Wg[(size_t)(c0 + c) * 128 + o];
    s += __shfl_xor(s, 1);
    if (h == 0) bqkv[1536 + o] = s;
  } else {                                    // ---- bqkv concat ----
    int i = (bid - 8609) * 256 + t;
    if (i < 1536)
      bqkv[i] = (i < 512) ? bq[i] : (i < 1024) ? bk[i - 512] : bv[i - 1024];
  }
}

// ---------------- bf16 MFMA GEMM, BK=64 single-buffer, XOR-swizzled LDS (r8 proven) ----
// C[M,N] = A[M,512] @ Wt[N,512]^T + bias. tile 128x128, 4 waves (2x2), wave 64x64.
// LDS rows 128B -> both-sides involution (rule 21): source chunk ^= row&7, reader ^= (row&7)<<4 B.
template<int OUT_BF16, int SWZ>
__global__ __launch_bounds__(256, 3) void gemm_kernel(
    const short* __restrict__ A,
    const short* __restrict__ Wt,
    const float* __restrict__ bias,
    void* __restrict__ Cp, int ldc, int nx)
{
  __shared__ short As[128 * 64];
  __shared__ short Bs[128 * 64];
  int id = blockIdx.x;
  if (SWZ) {                              // T1: contiguous tile chunk per XCD (grid%8==0)
    const int cpx = gridDim.x >> 3;
    id = (id & 7) * cpx + (id >> 3);
  }
  const int n0 = (id % nx) * 128;
  const int m0 = (id / nx) * 128;
  const int t = threadIdx.x;
  const int lane = t & 63, w = t >> 6;
  const int wm = (w >> 1) * 64, wn = (w & 1) * 64;
  const int lr = lane & 15;
  const int g8b = (lane >> 4) * 16;       // byte offset of k-frag (8 bf16)
  const int xorb = (lr & 7) << 4;         // reader swizzle (row&7)<<4 bytes

  const int srow = w * 8 + (lane >> 3);
  const int scol = (((lane & 7) ^ (lane >> 3)) << 4) >> 1;    // elems
  const short* Ag = A + (size_t)(m0 + srow) * 512 + scol;
  const short* Bg = Wt + (size_t)(n0 + srow) * 512 + scol;
  short* Al = &As[(w * 8) * 64];
  short* Bl = &Bs[(w * 8) * 64];

  f32x4 acc[4][4];
#pragma unroll
  for (int i = 0; i < 4; i++)
#pragma unroll
    for (int j = 0; j < 4; j++) acc[i][j] = (f32x4){0.f, 0.f, 0.f, 0.f};

  for (int k0 = 0; k0 < 512; k0 += 64) {
#pragma unroll
    for (int s = 0; s < 4; s++) {
      gload_lds16(Ag + k0 + s * (32 * 512), Al + s * (32 * 64));
      gload_lds16(Bg + k0 + s * (32 * 512), Bl + s * (32 * 64));
    }
    __syncthreads();                     // implicit vmcnt(0) drain
#pragma unroll
    for (int kk = 0; kk < 2; kk++) {
      bf16x8 af[4], bfr[4];
      const int ko = ((kk * 64 + g8b) ^ xorb) >> 1;   // swizzled elem offset in row
#pragma unroll
      for (int mt = 0; mt < 4; mt++) af[mt]  = *(bf16x8*)&As[(wm + mt * 16 + lr) * 64 + ko];
#pragma unroll
      for (int nt = 0; nt < 4; nt++) bfr[nt] = *(bf16x8*)&Bs[(wn + nt * 16 + lr) * 64 + ko];
#pragma unroll
      for (int mt = 0; mt < 4; mt++)
#pragma unroll
        for (int nt = 0; nt < 4; nt++)
          acc[mt][nt] = __builtin_amdgcn_mfma_f32_16x16x32_bf16(af[mt], bfr[nt], acc[mt][nt], 0, 0, 0);
    }
    __syncthreads();
  }

  const int cr = (lane >> 4) * 4;
#pragma unroll
  for (int nt = 0; nt < 4; nt++) {
    int col = n0 + wn + nt * 16 + lr;
    float bv = bias[col];
#pragma unroll
    for (int mt = 0; mt < 4; mt++) {
      int row = m0 + wm + mt * 16 + cr;
#pragma unroll
      for (int j = 0; j < 4; j++) {
        float v = acc[mt][nt][j] + bv;
        if (OUT_BF16) ((short*)Cp)[(size_t)(row + j) * ldc + col] = f2bf(v);
        else          ((float*)Cp)[(size_t)(row + j) * ldc + col] = v;
      }
    }
  }
}

// ---------------- fused windowed attention + combine (v5: split QK^T across wave pair) -
__global__ __launch_bounds__(256, 4) void winattn_combine_kernel(
    const short* __restrict__ qkvb, const short* __restrict__ xb,
    const float* __restrict__ kg, const float* __restrict__ kgo,
    const float* __restrict__ bgo, const float* __restrict__ pavg,
    const float* __restrict__ pmax, const float* __restrict__ conv_w,
    short* __restrict__ y)
{
  __shared__ short vs[2][16][512];            // V then xl, row-linear, data swizzled
  __shared__ float4 ps[2][2][64];             // partial S per (win, half, lane)
  __shared__ float4 esm[32];
  __shared__ float gateb[32];
  const int t = threadIdx.x;
  const int lane = t & 63, w = t >> 6;
  const int t0b = blockIdx.x * 32;            // block token base
  const int bb = t0b >> 12;                   // batch
  const int win = w >> 1, half = w & 1;
  const int t0 = t0b + win * 16;              // window token base

  // ---- V stage: wave covers rows half*8..+7 of its window; chunk l -> l^(r&7) ----
  {
    const int rb = half * 8;
#pragma unroll
    for (int i = 0; i < 8; i++) {
      const int r = rb + i;
      const short* vrow = &qkvb[(size_t)(t0 + r) * QKVS + 1024];
      gload_lds16(vrow + ((lane ^ (r & 7)) << 3), &vs[win][r][0]);
    }
  }

  // ---- QK^T (swapped), HALF k-range per wave: [half*256, half*256+256) ----
  const int qrow = lane & 15;
  const int grp8 = (lane >> 4) * 8;
  const int krow = (lane >> 4) * 4;
  const int colo = lane & 15;

  const short* kqbase = &qkvb[(size_t)(t0 + qrow) * QKVS];
  const int kb0 = half * 256;
  f32x4 accA = (f32x4){0.f, 0.f, 0.f, 0.f};
  f32x4 accB = (f32x4){0.f, 0.f, 0.f, 0.f};
#pragma unroll
  for (int k0 = 0; k0 < 256; k0 += 64) {
    bf16x8 kf0 = *(const bf16x8*)&kqbase[512 + kb0 + k0 + grp8];
    bf16x8 qf0 = *(const bf16x8*)&kqbase[kb0 + k0 + grp8];
    bf16x8 kf1 = *(const bf16x8*)&kqbase[512 + kb0 + k0 + 32 + grp8];
    bf16x8 qf1 = *(const bf16x8*)&kqbase[kb0 + k0 + 32 + grp8];
    accA = __builtin_amdgcn_mfma_f32_16x16x32_bf16(kf0, qf0, accA, 0, 0, 0);
    accB = __builtin_amdgcn_mfma_f32_16x16x32_bf16(kf1, qf1, accB, 0, 0, 0);
  }
  f32x4 part = accA + accB;
  ps[win][half][lane] = (float4){part[0], part[1], part[2], part[3]};

  // ---- gattn scores + conv gate: wave w -> tokens w*8..w*8+7, 8 lanes per token ----
  {
    const int tl = w * 8 + (lane >> 3);       // block-local token
    const int sub = lane & 7;                 // 16-elem slice
    const short* qr = &qkvb[(size_t)(t0b + tl) * QKVS + 1536 + sub * 16];
    bf16x8 qv0 = *(const bf16x8*)&qr[0];
    bf16x8 qv1 = *(const bf16x8*)&qr[8];
    const float* kr = &kg[bb * 512 + sub * 16];
    float p[4];
#pragma unroll
    for (int g = 0; g < 4; g++) {
      float4 ka = *(const float4*)&kr[g * 128];
      float4 kbv = *(const float4*)&kr[g * 128 + 4];
      float4 kc = *(const float4*)&kr[g * 128 + 8];
      float4 kd = *(const float4*)&kr[g * 128 + 12];
      float s = bf2f(qv0[0]) * ka.x + bf2f(qv0[1]) * ka.y + bf2f(qv0[2]) * ka.z + bf2f(qv0[3]) * ka.w
              + bf2f(qv0[4]) * kbv.x + bf2f(qv0[5]) * kbv.y + bf2f(qv0[6]) * kbv.z + bf2f(qv0[7]) * kbv.w
              + bf2f(qv1[0]) * kc.x + bf2f(qv1[1]) * kc.y + bf2f(qv1[2]) * kc.z + bf2f(qv1[3]) * kc.w
              + bf2f(qv1[4]) * kd.x + bf2f(qv1[5]) * kd.y + bf2f(qv1[6]) * kd.z + bf2f(qv1[7]) * kd.w;
      p[g] = s;
    }
#pragma unroll
    for (int off = 1; off < 8; off <<= 1) {
#pragma unroll
      for (int g = 0; g < 4; g++) p[g] += __shfl_xor(p[g], off);
    }
    if (sub == 0) {
      const float gs = 0.08838834764831845f;  // 1/sqrt(128)
      float p0 = p[0] * gs, p1 = p[1] * gs, p2 = p[2] * gs, p3 = p[3] * gs;
      float mx = fmaxf(fmaxf(p0, p1), fmaxf(p2, p3));
      float e0 = __expf(p0 - mx), e1 = __expf(p1 - mx), e2 = __expf(p2 - mx), e3 = __expf(p3 - mx);
      float inv = 1.0f / (e0 + e1 + e2 + e3);
      esm[tl] = make_float4(e0 * inv, e1 * inv, e2 * inv, e3 * inv);
      int s = (t0b + tl) & 4095;
      float g = 0.f;
#pragma unroll
      for (int tk = 0; tk < 7; tk++) {
        int ss = s + tk - 3;
        if (ss >= 0 && ss < SS)
          g += conv_w[tk] * pavg[bb * SS + ss] + conv_w[7 + tk] * pmax[bb * SS + ss];
      }
      gateb[tl] = 1.0f / (1.0f + __expf(-g));
    }
  }

  __syncthreads();      // drains V gloads; publishes ps / esm / gateb

  // ---- combine partner partial + softmax over 16 keys ----
  const float4 oth = ps[win][half ^ 1][lane];
  const float scale = 0.04419417382415922f;   // 1/sqrt(512)
  float s0 = (part[0] + oth.x) * scale, s1 = (part[1] + oth.y) * scale;
  float s2 = (part[2] + oth.z) * scale, s3 = (part[3] + oth.w) * scale;
  float m = fmaxf(fmaxf(s0, s1), fmaxf(s2, s3));
  m = fmaxf(m, __shfl_xor(m, 16));
  m = fmaxf(m, __shfl_xor(m, 32));
  float e0 = __expf(s0 - m), e1 = __expf(s1 - m), e2 = __expf(s2 - m), e3 = __expf(s3 - m);
  float sum = e0 + e1 + e2 + e3;
  sum += __shfl_xor(sum, 16);
  sum += __shfl_xor(sum, 32);
  float inv = 1.0f / sum;
  s16x4 pa;
  pa[0] = f2bf(e0 * inv); pa[1] = f2bf(e1 * inv);
  pa[2] = f2bf(e2 * inv); pa[3] = f2bf(e3 * inv);

  // ---- PV: read V from LDS (swizzled), mfma, overwrite consumed subtile with xl ----
#pragma unroll
  for (int ct = 0; ct < 16; ct++) {
    const int cb = (half * 256 + ct * 16 + colo) * 2;   // byte offset in row
    s16x4 bf;
#pragma unroll
    for (int u = 0; u < 4; u++) {
      const int r = krow + u;
      bf[u] = vs[win][r][(cb ^ ((r & 7) << 4)) >> 1];
    }
    f32x4 d = pv_mfma(pa, bf, (f32x4){0.f, 0.f, 0.f, 0.f});
#pragma unroll
    for (int jj = 0; jj < 4; jj++) {
      const int r = krow + jj;                          // D row = q index
      vs[win][r][(cb ^ ((r & 7) << 4)) >> 1] = f2bf(d[jj]);
    }
  }
  __syncthreads();

  // ---- vectorized combine: thread -> (row r=t>>3, cols (t&7)*8 + 64*it) ----
  const int r = t >> 3;
  const int rowg = t0b + r;
  const int winr = r >> 4, rr = r & 15;
  const float4 e = esm[r];
  const float g = gateb[r];
  const float* kgr = &kgo[bb * 2048];
  const short* xrow = &xb[(size_t)rowg * CC];
  const short* xlrow = &vs[winr][rr][0];
  short* yrow = &y[(size_t)rowg * CC];
#pragma unroll
  for (int it = 0; it < 8; it++) {
    const int c = (t & 7) * 8 + it * 64;
    bf16x8 xv  = *(const bf16x8*)&xrow[c];
    bf16x8 xlv = *(const bf16x8*)&xlrow[((c * 2) ^ ((rr & 7) << 4)) >> 1];
    float4 k0a = *(const float4*)&kgr[c],        k0b = *(const float4*)&kgr[c + 4];
    float4 k1a = *(const float4*)&kgr[512 + c],  k1b = *(const float4*)&kgr[512 + c + 4];
    float4 k2a = *(const float4*)&kgr[1024 + c], k2b = *(const float4*)&kgr[1024 + c + 4];
    float4 k3a = *(const float4*)&kgr[1536 + c], k3b = *(const float4*)&kgr[1536 + c + 4];
    float4 ba  = *(const float4*)&bgo[c],        bbv = *(const float4*)&bgo[c + 4];
    float xg[8];
    xg[0] = e.x * k0a.x + e.y * k1a.x + e.z * k2a.x + e.w * k3a.x + ba.x;
    xg[1] = e.x * k0a.y + e.y * k1a.y + e.z * k2a.y + e.w * k3a.y + ba.y;
    xg[2] = e.x * k0a.z + e.y * k1a.z + e.z * k2a.z + e.w * k3a.z + ba.z;
    xg[3] = e.x * k0a.w + e.y * k1a.w + e.z * k2a.w + e.w * k3a.w + ba.w;
    xg[4] = e.x * k0b.x + e.y * k1b.x + e.z * k2b.x + e.w * k3b.x + bbv.x;
    xg[5] = e.x * k0b.y + e.y * k1b.y + e.z * k2b.y + e.w * k3b.y + bbv.y;
    xg[6] = e.x * k0b.z + e.y * k1b.z + e.z * k2b.z + e.w * k3b.z + bbv.z;
    xg[7] = e.x * k0b.w + e.y * k1b.w + e.z * k2b.w + e.w * k3b.w + bbv.w;
    bf16x8 ov;
#pragma unroll
    for (int u = 0; u < 8; u++)
      ov[u] = f2bf((bf2f(xv[u]) + bf2f(xlv[u]) + xg[u]) * g);
    *(bf16x8*)&yrow[c] = ov;
  }
}

// ---------------- launcher ----------------
extern "C" void kernel_launch(void* const* d_in, const int* in_sizes, int n_in,
                              void* d_out, int out_size, void* d_ws, size_t ws_size,
                              hipStream_t stream)
{
  const float* x     = (const float*)d_in[0];
  const float* Wq    = (const float*)d_in[1];
  const float* bq    = (const float*)d_in[2];
  const float* Wk    = (const float*)d_in[3];
  const float* bk    = (const float*)d_in[4];
  const float* Wv    = (const float*)d_in[5];
  const float* bv    = (const float*)d_in[6];
  const float* Wo    = (const float*)d_in[7];
  const float* bo    = (const float*)d_in[8];
  const float* Wg    = (const float*)d_in[9];
  const float* bg    = (const float*)d_in[10];
  const float* Wgo   = (const float*)d_in[11];
  const float* bgo   = (const float*)d_in[12];
  const float* convw = (const float*)d_in[13];
  float* out = (float*)d_out;

  char* ws = (char*)d_ws;
  size_t off = 0;
  auto alloc = [&](size_t bytes) -> void* {
    void* p = ws + off;
    off += (bytes + 255) & ~(size_t)255;
    return p;
  };
  short* xb    = (short*)alloc((size_t)NTOK * CC * 2);           // 33.5 MB
  short* qkvb  = (short*)alloc((size_t)NTOK * QKVS * 2);         // 109 MB
  short* WtQKV = (short*)alloc((size_t)QKVS * 512 * 2);          // [q|k|v|WqWg] rows
  short* WtO   = (short*)alloc((size_t)512 * 512 * 2);
  float* bqkv  = (float*)alloc(QKVS * 4);
  float* kg    = (float*)alloc(8 * 4 * 128 * 4);
  float* kgo   = (float*)alloc(8 * 4 * 512 * 4);
  float* pavg  = (float*)alloc((size_t)NTOK * 4);
  float* pmax  = (float*)alloc((size_t)NTOK * 4);
  short* ybuf  = (short*)alloc((size_t)NTOK * CC * 2);           // 33.5 MB (final y)

  // all front work in one launch (fold now LDS-staged + coalesced Wg reads)
  front_kernel<<<8615, 256, 0, stream>>>(x, Wq, Wk, Wv, Wo, Wg, bq, bk, bv, bg, Wgo,
                                         xb, pavg, pmax, WtQKV, WtO, bqkv, kg, kgo);

  // qkv|qg = x @ [Wq|Wk|Wv|WqWg] + [bq|bk|bv|bqg]  (M=32768, N=1664), nwg=3328
  gemm_kernel<1, 1><<<13 * 256, 256, 0, stream>>>(xb, WtQKV, bqkv, qkvb, QKVS, 13);

  // fused window-attention + global-attn combine + gate -> y (bf16)
  winattn_combine_kernel<<<NTOK / 32, 256, 0, stream>>>(qkvb, xb, kg, kgo, bgo,
                                                        pavg, pmax, convw, ybuf);

  // out = y @ Wo + bo  (M=32768, N=512, fp32 out), nwg=1024
  gemm_kernel<0, 1><<<4 * 256, 256, 0, stream>>>(ybuf, WtO, bo, out, CC, 4);
}